// Round 6
// baseline (212.670 us; speedup 1.0000x reference)
//
#include <hip/hip_runtime.h>
#include <math.h>

#define BATCHN 2
#define SEQ 2048
#define DMODEL 2048
#define NH 32
#define NKV 8
#define HDIM 64
#define KVD 512          // NKV*HDIM
#define ROWS 4096        // BATCHN*SEQ

typedef __bf16 bf16x8 __attribute__((ext_vector_type(8)));
typedef float f32x4 __attribute__((ext_vector_type(4)));
typedef unsigned short u16x8 __attribute__((ext_vector_type(8)));

#define MFMA(a, b, c) __builtin_amdgcn_mfma_f32_16x16x32_bf16(a, b, c, 0, 0, 0)

__device__ __forceinline__ unsigned short f2bf(float f) {
  union { float f; unsigned u; } v; v.f = f;
  unsigned u = v.u;
  u += 0x7fffu + ((u >> 16) & 1u);   // RNE
  return (unsigned short)(u >> 16);
}

__device__ __forceinline__ unsigned cvtpk(float a, float b) {
  unsigned r;
  asm("v_cvt_pk_bf16_f32 %0, %1, %2" : "=v"(r) : "v"(a), "v"(b));
  return r;
}
__device__ __forceinline__ void pl32(unsigned& a, unsigned& b) {
  asm("v_permlane32_swap_b32 %0, %1" : "+v"(a), "+v"(b));
}
__device__ __forceinline__ void pl16(unsigned& a, unsigned& b) {
  asm("v_permlane16_swap_b32 %0, %1" : "+v"(a), "+v"(b));
}
__device__ __forceinline__ float exp2v(float x) {
  float r;
  asm("v_exp_f32 %0, %1" : "=v"(r) : "v"(x));
  return r;
}

// async global->LDS, 16B per lane; LDS dest = wave-uniform base + lane*16 (HW rule)
__device__ __forceinline__ void gload16(const void* g, void* l) {
  __builtin_amdgcn_global_load_lds((const __attribute__((address_space(1))) unsigned int*)g,
                                   (__attribute__((address_space(3))) unsigned int*)l, 16, 0, 0);
}

#define FENCE() asm volatile("" ::: "memory")
#define BARRIER() do { FENCE(); __builtin_amdgcn_s_barrier(); FENCE(); } while (0)
#define LGKM0() asm volatile("s_waitcnt lgkmcnt(0)" ::: "memory")
#define VMCNT(n) asm volatile("s_waitcnt vmcnt(" #n ")" ::: "memory")

// ---------------- fused fp32->bf16 conversions + RoPE tables (one launch) ----------------
__global__ __launch_bounds__(256) void conv_all(const float* __restrict__ x,
                                                const float* __restrict__ Wq,
                                                const float* __restrict__ Wk,
                                                const float* __restrict__ Wv,
                                                const float* __restrict__ Wo,
                                                unsigned short* __restrict__ xb,
                                                unsigned short* __restrict__ Wqb,
                                                unsigned short* __restrict__ Wkb,
                                                unsigned short* __restrict__ Wvb,
                                                unsigned short* __restrict__ Wob,
                                                float* __restrict__ ct,
                                                float* __restrict__ st) {
  int i = blockIdx.x * 256 + threadIdx.x;
  const float* in;
  unsigned short* out;
  int off;
  if (i < 2097152)      { in = x;  out = xb;  off = i; }
  else if (i < 3145728) { in = Wq; out = Wqb; off = i - 2097152; }
  else if (i < 3407872) { in = Wk; out = Wkb; off = i - 3145728; }
  else if (i < 3670016) { in = Wv; out = Wvb; off = i - 3407872; }
  else if (i < 4718592) { in = Wo; out = Wob; off = i - 3670016; }
  else {
    int t = i - 4718592;  // 0..65535 : RoPE tables [SEQ][32]
    int s = t >> 5, f = t & 31;
    float inv = __expf(-(float)f * (9.210340371976184f / 32.0f));  // 10000^(-f/32)
    float ang = (float)s * inv;
    ct[t] = cosf(ang);
    st[t] = sinf(ang);
    return;
  }
  float4 v = ((const float4*)in)[off];
  ushort4 o;
  o.x = f2bf(v.x); o.y = f2bf(v.y); o.z = f2bf(v.z); o.w = f2bf(v.w);
  ((ushort4*)out)[off] = o;
}

// ================= QKV GEMM: 256x256 tile, BK=64, 8 waves, 4-phase, counted vmcnt =================
// Per-wave 128x64 output (8mf x 4nf). Half-tile staging ledger:
//   tile T halves staged at: A0:(T-2)p3  A1:(T-1)p0  B0:(T-1)p1  B1:(T-1)p2
//   at each p3: stage(T+2,A0) then vmcnt(2) -> all of tile T+1 resident.
__global__ __launch_bounds__(512) void gemm_qkv256(const unsigned short* __restrict__ A,
                                                   const unsigned short* __restrict__ Bq,
                                                   const unsigned short* __restrict__ Bk,
                                                   const unsigned short* __restrict__ Bv,
                                                   unsigned short* __restrict__ Qo,
                                                   unsigned short* __restrict__ Ko,
                                                   unsigned short* __restrict__ Vo,
                                                   const float* __restrict__ ct,
                                                   const float* __restrict__ st) {
  __shared__ __align__(16) unsigned short Als[2][2][8192];   // [buf][half][128*64]
  __shared__ __align__(16) unsigned short Bls[2][2][8192];
  const int tid = threadIdx.x, lane = tid & 63, wv = tid >> 6;
  const int wm = wv >> 2, wn = wv & 3;
  const int g = lane >> 4, r15 = lane & 15;
  // 192 blocks; XCD chunks of 24, bm-major (bn fastest) -> 2 A-panels per L2
  const int wgid = (blockIdx.x & 7) * 24 + (blockIdx.x >> 3);
  const int bm = wgid / 12, bn = wgid % 12;
  const int row0 = bm << 8;
  const unsigned short* Bp;
  unsigned short* Outb;
  int col0, ldo, rope, qsc;
  if (bn < 8)       { Bp = Bq; Outb = Qo; col0 = bn << 8;        ldo = DMODEL; rope = 1; qsc = 1; }
  else if (bn < 10) { Bp = Bk; Outb = Ko; col0 = (bn - 8) << 8;  ldo = KVD;    rope = 1; qsc = 0; }
  else              { Bp = Bv; Outb = Vo; col0 = (bn - 10) << 8; ldo = KVD;    rope = 0; qsc = 0; }
  // staging: thread -> (row srl, pre-swizzled 16B granule); half = 2 sweeps of 64 rows
  const int srl = tid >> 3;
  const int sgc = ((tid & 7) ^ (srl & 7)) << 3;  // shorts
  const unsigned short* gA = A + (size_t)(row0 + srl) * DMODEL + sgc;
  const unsigned short* gB = Bp + (size_t)(col0 + srl) * DMODEL + sgc;

  f32x4 acc[8][4];
#pragma unroll
  for (int i = 0; i < 8; ++i)
#pragma unroll
    for (int jj = 0; jj < 4; ++jj) acc[i][jj] = (f32x4){0.f, 0.f, 0.f, 0.f};

#define STG_A(buf, h, kt) do { \
    gload16(gA + (size_t)((h) * 128) * DMODEL + (kt) * 64, &Als[buf][h][(wv << 9)]); \
    gload16(gA + (size_t)((h) * 128 + 64) * DMODEL + (kt) * 64, &Als[buf][h][4096 + (wv << 9)]); } while (0)
#define STG_B(buf, h, kt) do { \
    gload16(gB + (size_t)((h) * 128) * DMODEL + (kt) * 64, &Bls[buf][h][(wv << 9)]); \
    gload16(gB + (size_t)((h) * 128 + 64) * DMODEL + (kt) * 64, &Bls[buf][h][4096 + (wv << 9)]); } while (0)
#define RA(buf, mf, kk) (*(const bf16x8*)&Als[buf][wm][((mf) * 16 + r15) * 64 + \
                          (((((kk) << 2) + g) ^ (r15 & 7)) << 3)])
#define RB(buf, nf, kk) (*(const bf16x8*)&Bls[buf][wn >> 1][((wn & 1) * 64 + (nf) * 16 + r15) * 64 + \
                          (((((kk) << 2) + g) ^ (r15 & 7)) << 3)])

  // prologue: tile0 all, tile1 A0
  STG_A(0, 0, 0); STG_A(0, 1, 0); STG_B(0, 0, 0); STG_B(0, 1, 0); STG_A(1, 0, 1);
  VMCNT(2);
  BARRIER();

  const int NT = DMODEL / 64;  // 32
  for (int t = 0; t < NT; ++t) {
    const int cur = t & 1;
    // ---- phase 0: A03 + B01 reads; MFMA q0 ----
    bf16x8 a0[4][2], b0[2][2];
#pragma unroll
    for (int mf = 0; mf < 4; ++mf) { a0[mf][0] = RA(cur, mf, 0); a0[mf][1] = RA(cur, mf, 1); }
#pragma unroll
    for (int nf = 0; nf < 2; ++nf) { b0[nf][0] = RB(cur, nf, 0); b0[nf][1] = RB(cur, nf, 1); }
    if (t + 1 < NT) STG_A(cur ^ 1, 1, t + 1);
    BARRIER(); LGKM0();
    __builtin_amdgcn_s_setprio(1);
#pragma unroll
    for (int mf = 0; mf < 4; ++mf)
#pragma unroll
      for (int nf = 0; nf < 2; ++nf) {
        acc[mf][nf] = MFMA(a0[mf][0], b0[nf][0], acc[mf][nf]);
        acc[mf][nf] = MFMA(a0[mf][1], b0[nf][1], acc[mf][nf]);
      }
    __builtin_amdgcn_s_setprio(0);
    BARRIER();
    // ---- phase 1: B23 reads; MFMA q1 (A03 held) ----
    bf16x8 b2[2][2];
#pragma unroll
    for (int nf = 0; nf < 2; ++nf) { b2[nf][0] = RB(cur, 2 + nf, 0); b2[nf][1] = RB(cur, 2 + nf, 1); }
    if (t + 1 < NT) STG_B(cur ^ 1, 0, t + 1);
    BARRIER(); LGKM0();
    __builtin_amdgcn_s_setprio(1);
#pragma unroll
    for (int mf = 0; mf < 4; ++mf)
#pragma unroll
      for (int nf = 0; nf < 2; ++nf) {
        acc[mf][2 + nf] = MFMA(a0[mf][0], b2[nf][0], acc[mf][2 + nf]);
        acc[mf][2 + nf] = MFMA(a0[mf][1], b2[nf][1], acc[mf][2 + nf]);
      }
    __builtin_amdgcn_s_setprio(0);
    BARRIER();
    // ---- phase 2: A47 reads; MFMA q3 (B23 held) ----
    bf16x8 a4[4][2];
#pragma unroll
    for (int mf = 0; mf < 4; ++mf) { a4[mf][0] = RA(cur, 4 + mf, 0); a4[mf][1] = RA(cur, 4 + mf, 1); }
    if (t + 1 < NT) STG_B(cur ^ 1, 1, t + 1);
    BARRIER(); LGKM0();
    __builtin_amdgcn_s_setprio(1);
#pragma unroll
    for (int mf = 0; mf < 4; ++mf)
#pragma unroll
      for (int nf = 0; nf < 2; ++nf) {
        acc[4 + mf][2 + nf] = MFMA(a4[mf][0], b2[nf][0], acc[4 + mf][2 + nf]);
        acc[4 + mf][2 + nf] = MFMA(a4[mf][1], b2[nf][1], acc[4 + mf][2 + nf]);
      }
    __builtin_amdgcn_s_setprio(0);
    BARRIER();
    // ---- phase 3: no reads; stage next A0 + counted vmcnt; MFMA q2 (A47,B01 held) ----
    if (t + 2 < NT) { STG_A(cur, 0, t + 2); VMCNT(2); }
    else if (t + 1 < NT) VMCNT(0);
    BARRIER();
    __builtin_amdgcn_s_setprio(1);
#pragma unroll
    for (int mf = 0; mf < 4; ++mf)
#pragma unroll
      for (int nf = 0; nf < 2; ++nf) {
        acc[4 + mf][nf] = MFMA(a4[mf][0], b0[nf][0], acc[4 + mf][nf]);
        acc[4 + mf][nf] = MFMA(a4[mf][1], b0[nf][1], acc[4 + mf][nf]);
      }
    __builtin_amdgcn_s_setprio(0);
    BARRIER();
  }
#undef STG_A
#undef STG_B
#undef RA
#undef RB

  const float QS = 0.18033688011112042f;  // 0.125 * log2(e)
#pragma unroll
  for (int mf = 0; mf < 8; ++mf) {
#pragma unroll
    for (int rr = 0; rr < 4; ++rr) {
      const int m = row0 + (wm << 7) + (mf << 4) + (g << 2) + rr;
      const float* ctr = ct + ((m & (SEQ - 1)) << 5);
      const float* str = st + ((m & (SEQ - 1)) << 5);
#pragma unroll
      for (int nf = 0; nf < 4; ++nf) {
        const int n = col0 + (wn << 6) + (nf << 4) + r15;
        float v = acc[mf][nf][rr];
        float p = __shfl_xor(v, 1);
        if (rope) {
          int fi = (n & 63) >> 1;
          float c = ctr[fi], sn = str[fi];
          v = (lane & 1) ? (p * sn + v * c) : (v * c - p * sn);
        }
        if (qsc) v *= QS;
        Outb[(size_t)m * ldo + n] = f2bf(v);
      }
    }
  }
}

// ================= out-proj GEMM: 128x256 tile, BK=64, 8 waves, 2-phase, counted vmcnt =================
// Per-wave 64x64 (4mf x 4nf). Ledger: tile T: A:(T-2)p1, B0/B1:(T-1)p0; at p1 stage(T+2,A)+vmcnt(2).
__global__ __launch_bounds__(512) void gemm_out128(const unsigned short* __restrict__ A,
                                                   const unsigned short* __restrict__ B,
                                                   float* __restrict__ C) {
  __shared__ __align__(16) unsigned short Als[2][8192];      // [buf][128*64]
  __shared__ __align__(16) unsigned short Bls[2][2][8192];   // [buf][half][128*64]
  const int tid = threadIdx.x, lane = tid & 63, wv = tid >> 6;
  const int wm = wv >> 2, wn = wv & 3;
  const int g = lane >> 4, r15 = lane & 15;
  // 256 blocks; XCD chunks of 32, bm-major (bn fastest)
  const int wgid = (blockIdx.x & 7) * 32 + (blockIdx.x >> 3);
  const int bm = wgid >> 3, bn = wgid & 7;
  const int row0 = bm << 7, col0 = bn << 8;
  const int srl = tid >> 3;
  const int sgc = ((tid & 7) ^ (srl & 7)) << 3;
  const unsigned short* gA = A + (size_t)(row0 + srl) * DMODEL + sgc;
  const unsigned short* gB = B + (size_t)(col0 + srl) * DMODEL + sgc;

  f32x4 acc[4][4];
#pragma unroll
  for (int i = 0; i < 4; ++i)
#pragma unroll
    for (int jj = 0; jj < 4; ++jj) acc[i][jj] = (f32x4){0.f, 0.f, 0.f, 0.f};

#define STG_A1(buf, kt) do { \
    gload16(gA + (size_t)(kt) * 64, &Als[buf][(wv << 9)]); \
    gload16(gA + (size_t)64 * DMODEL + (size_t)(kt) * 64, &Als[buf][4096 + (wv << 9)]); } while (0)
#define STG_B1(buf, h, kt) do { \
    gload16(gB + (size_t)((h) * 128) * DMODEL + (kt) * 64, &Bls[buf][h][(wv << 9)]); \
    gload16(gB + (size_t)((h) * 128 + 64) * DMODEL + (kt) * 64, &Bls[buf][h][4096 + (wv << 9)]); } while (0)
#define RA1(buf, mf, kk) (*(const bf16x8*)&Als[buf][((wm << 6) + (mf) * 16 + r15) * 64 + \
                           (((((kk) << 2) + g) ^ (r15 & 7)) << 3)])
#define RB1(buf, nf, kk) (*(const bf16x8*)&Bls[buf][wn >> 1][((wn & 1) * 64 + (nf) * 16 + r15) * 64 + \
                           (((((kk) << 2) + g) ^ (r15 & 7)) << 3)])

  STG_A1(0, 0); STG_B1(0, 0, 0); STG_B1(0, 1, 0); STG_A1(1, 1);
  VMCNT(2);
  BARRIER();

  const int NT = DMODEL / 64;  // 32
  for (int t = 0; t < NT; ++t) {
    const int cur = t & 1;
    // ---- phase 0: A + B01 reads; stage next B; MFMA left half ----
    bf16x8 a[4][2], b0[2][2];
#pragma unroll
    for (int mf = 0; mf < 4; ++mf) { a[mf][0] = RA1(cur, mf, 0); a[mf][1] = RA1(cur, mf, 1); }
#pragma unroll
    for (int nf = 0; nf < 2; ++nf) { b0[nf][0] = RB1(cur, nf, 0); b0[nf][1] = RB1(cur, nf, 1); }
    if (t + 1 < NT) { STG_B1(cur ^ 1, 0, t + 1); STG_B1(cur ^ 1, 1, t + 1); }
    BARRIER(); LGKM0();
    __builtin_amdgcn_s_setprio(1);
#pragma unroll
    for (int mf = 0; mf < 4; ++mf)
#pragma unroll
      for (int nf = 0; nf < 2; ++nf) {
        acc[mf][nf] = MFMA(a[mf][0], b0[nf][0], acc[mf][nf]);
        acc[mf][nf] = MFMA(a[mf][1], b0[nf][1], acc[mf][nf]);
      }
    __builtin_amdgcn_s_setprio(0);
    BARRIER();
    // ---- phase 1: B23 reads; stage next A + counted vmcnt; MFMA right half ----
    bf16x8 b2[2][2];
#pragma unroll
    for (int nf = 0; nf < 2; ++nf) { b2[nf][0] = RB1(cur, 2 + nf, 0); b2[nf][1] = RB1(cur, 2 + nf, 1); }
    if (t + 2 < NT) { STG_A1(cur, t + 2); VMCNT(2); }
    else if (t + 1 < NT) VMCNT(0);
    BARRIER(); LGKM0();
    __builtin_amdgcn_s_setprio(1);
#pragma unroll
    for (int mf = 0; mf < 4; ++mf)
#pragma unroll
      for (int nf = 0; nf < 2; ++nf) {
        acc[mf][2 + nf] = MFMA(a[mf][0], b2[nf][0], acc[mf][2 + nf]);
        acc[mf][2 + nf] = MFMA(a[mf][1], b2[nf][1], acc[mf][2 + nf]);
      }
    __builtin_amdgcn_s_setprio(0);
    BARRIER();
  }
#undef STG_A1
#undef STG_B1
#undef RA1
#undef RB1

#pragma unroll
  for (int mf = 0; mf < 4; ++mf)
#pragma unroll
    for (int rr = 0; rr < 4; ++rr) {
      const int m = row0 + (wm << 6) + (mf << 4) + (g << 2) + rr;
#pragma unroll
      for (int nf = 0; nf < 4; ++nf)
        C[(size_t)m * DMODEL + col0 + (wn << 6) + (nf << 4) + r15] = acc[mf][nf][rr];
    }
}

// ---------------- V transpose via LDS tile: (B*S, KVD) -> (B, NKV, HDIM, S) ----------------
__global__ __launch_bounds__(256) void transpose_v(const unsigned short* __restrict__ V,
                                                   unsigned short* __restrict__ Vt) {
  __shared__ unsigned short t[64][80];
  const int bid = blockIdx.x;       // 512 = 2*8*32
  const int st_ = bid & 31;
  const int kvh = (bid >> 5) & 7;
  const int b = bid >> 8;
  const int tid = threadIdx.x;
#pragma unroll
  for (int p = 0; p < 2; ++p) {
    int idx = p * 2048 + tid * 8;
    int r = idx >> 6, c = idx & 63;
    u16x8 v = *(const u16x8*)(V + (size_t)(b * SEQ + st_ * 64 + r) * KVD + kvh * 64 + c);
#pragma unroll
    for (int jj = 0; jj < 8; ++jj) t[c + jj][r] = v[jj];
  }
  __syncthreads();
#pragma unroll
  for (int p = 0; p < 2; ++p) {
    int idx = p * 2048 + tid * 8;
    int d = idx >> 6, s = idx & 63;
    u16x8 v = *(const u16x8*)&t[d][s];
    *(u16x8*)(Vt + (size_t)((b * NKV + kvh) * HDIM + d) * SEQ + st_ * 64 + s) = v;
  }
}

// ---------------- Flash attention (causal, GQA) ----------------
__global__ __launch_bounds__(256) void attn_fwd(const unsigned short* __restrict__ Q,
                                                const unsigned short* __restrict__ K,
                                                const unsigned short* __restrict__ Vt,
                                                unsigned short* __restrict__ O) {
  __shared__ __align__(16) unsigned short Kls[2][64 * 64];
  __shared__ __align__(16) unsigned short Vls[2][64 * 64];
  const int bid = blockIdx.x;
  const int xcd = bid & 7;
  const int within = bid >> 3;             // 0..127
  const int grp = xcd * 2 + (within >> 6); // 0..15 = (b,kvh)
  const int w64 = within & 63;
  const int j = w64 & 15;                  // pair: tiles j and 31-j
  const int hsub = w64 >> 4;
  const int b = grp >> 3, kvh = grp & 7;
  const int h = kvh * 4 + hsub;
  const int wave = threadIdx.x >> 6, lane = threadIdx.x & 63;
  const int g = lane >> 4, r15 = lane & 15;
  const int sr = lane >> 3;
  const int sc = (((lane & 7) << 4) ^ (sr << 4)) >> 1;  // pre-swizzled src col (shorts)
  const unsigned short* kbase = K + (size_t)b * SEQ * KVD + kvh * HDIM;
  const unsigned short* vbase = Vt + (size_t)((b * NKV + kvh) * HDIM) * SEQ;

  union { u16x8 s; bf16x8 v; } one8;
#pragma unroll
  for (int z = 0; z < 8; ++z) one8.s[z] = 0x3F80;  // bf16 1.0

  auto STAGE = [&](int bi, int kbv) {
#pragma unroll
    for (int i = 0; i < 2; ++i) {
      const int r = wave * 16 + i * 8;
      gload16(kbase + (size_t)(kbv + r + sr) * KVD + sc, &Kls[bi][r * 64]);
      gload16(vbase + (size_t)(r + sr) * SEQ + kbv + sc, &Vls[bi][r * 64]);
    }
  };

#pragma unroll 1
  for (int sel = 0; sel < 2; ++sel) {
    const int qt = sel ? (31 - j) : j;
    const int qrow0 = qt * 64 + wave * 16;
    const unsigned short* qp = Q + (size_t)(b * SEQ + qrow0 + r15) * DMODEL + h * HDIM;
    bf16x8 q0 = *(const bf16x8*)(qp + g * 8);
    bf16x8 q1 = *(const bf16x8*)(qp + 32 + g * 8);
    f32x4 oacc[4] = {};
    f32x4 lacc = {};
    const int kend = (qt + 1) * 64;
    __syncthreads();           // prior-tile reads drained before restaging
    STAGE(0, 0);
    int buf = 0;
    for (int kb = 0; kb < kend; kb += 64) {
      __syncthreads();         // staged loads for buf complete; buf^1 reads done
      if (kb + 64 < kend) STAGE(buf ^ 1, kb + 64);
      const char* Kc = (const char*)&Kls[buf][0];
      const char* Vc = (const char*)&Vls[buf][0];
      f32x4 s[4];
      __builtin_amdgcn_s_setprio(1);
#pragma unroll
      for (int f = 0; f < 4; ++f) {
        const int r = f * 16 + r15;
        const int sw = (r & 7) << 4;
        bf16x8 k0 = *(const bf16x8*)(Kc + r * 128 + ((g * 16) ^ sw));
        bf16x8 k1 = *(const bf16x8*)(Kc + r * 128 + ((64 + g * 16) ^ sw));
        f32x4 z = {};
        s[f] = MFMA(k1, q1, MFMA(k0, q0, z));
      }
      __builtin_amdgcn_s_setprio(0);
      if (kb + 64 == kend) {   // diagonal tile: causal mask
        const int q = qrow0 + r15;
#pragma unroll
        for (int f = 0; f < 4; ++f)
#pragma unroll
          for (int rr = 0; rr < 4; ++rr)
            if (kb + f * 16 + g * 4 + rr > q) s[f][rr] = -1e30f;
      }
#pragma unroll
      for (int f = 0; f < 4; ++f)
#pragma unroll
        for (int rr = 0; rr < 4; ++rr) s[f][rr] = exp2v(s[f][rr]);
      // C-layout -> A-layout in-register (cvt_pk + permlane swaps)
      bf16x8 p1, p2;
      {
        union { bf16x8 v; unsigned u[4]; } P1, P2;
        unsigned a0 = cvtpk(s[0][0], s[0][1]), b0 = cvtpk(s[1][0], s[1][1]);
        pl32(a0, b0); pl16(a0, b0);
        unsigned a1 = cvtpk(s[0][2], s[0][3]), b1 = cvtpk(s[1][2], s[1][3]);
        pl32(a1, b1); pl16(a1, b1);
        P1.u[0] = a0; P1.u[1] = a1; P1.u[2] = b0; P1.u[3] = b1;
        unsigned a2 = cvtpk(s[2][0], s[2][1]), b2 = cvtpk(s[3][0], s[3][1]);
        pl32(a2, b2); pl16(a2, b2);
        unsigned a3 = cvtpk(s[2][2], s[2][3]), b3 = cvtpk(s[3][2], s[3][3]);
        pl32(a3, b3); pl16(a3, b3);
        P2.u[0] = a2; P2.u[1] = a3; P2.u[2] = b2; P2.u[3] = b3;
        p1 = P1.v; p2 = P2.v;
      }
      // l[q] accumulated on MFMA pipe: D rows (g*4+rr) = q, cols identical
      lacc = MFMA(p2, one8.v, MFMA(p1, one8.v, lacc));
      __builtin_amdgcn_s_setprio(1);
#pragma unroll
      for (int dc = 0; dc < 4; ++dc) {
        const int r = dc * 16 + r15;
        const int sw = (r & 7) << 4;
        bf16x8 v0 = *(const bf16x8*)(Vc + r * 128 + ((g * 16) ^ sw));
        bf16x8 v1 = *(const bf16x8*)(Vc + r * 128 + ((64 + g * 16) ^ sw));
        oacc[dc] = MFMA(p2, v1, MFMA(p1, v0, oacc[dc]));
      }
      __builtin_amdgcn_s_setprio(0);
      buf ^= 1;
    }
    float rls[4];
#pragma unroll
    for (int rr = 0; rr < 4; ++rr) rls[rr] = 1.0f / lacc[rr];
    unsigned short* optr = O + (size_t)(b * SEQ + qrow0) * DMODEL + h * HDIM;
#pragma unroll
    for (int dc = 0; dc < 4; ++dc)
#pragma unroll
      for (int rr = 0; rr < 4; ++rr)
        optr[(size_t)(g * 4 + rr) * DMODEL + dc * 16 + r15] = f2bf(oacc[dc][rr] * rls[rr]);
  }
}

extern "C" void kernel_launch(void* const* d_in, const int* in_sizes, int n_in,
                              void* d_out, int out_size, void* d_ws, size_t ws_size,
                              hipStream_t stream) {
  const float* x  = (const float*)d_in[0];
  const float* Wq = (const float*)d_in[1];
  const float* Wk = (const float*)d_in[2];
  const float* Wv = (const float*)d_in[3];
  const float* Wo = (const float*)d_in[4];

  char* ws = (char*)d_ws;
  unsigned short* xb  = (unsigned short*)(ws);                    // 16 MiB
  unsigned short* Wqb = (unsigned short*)(ws + (16u << 20));      // 8 MiB
  unsigned short* Wkb = (unsigned short*)(ws + (24u << 20));      // 2 MiB
  unsigned short* Wvb = (unsigned short*)(ws + (26u << 20));      // 2 MiB
  unsigned short* Wob = (unsigned short*)(ws + (28u << 20));      // 8 MiB
  unsigned short* Qb  = (unsigned short*)(ws + (36u << 20));      // 16 MiB
  unsigned short* Kb  = (unsigned short*)(ws + (52u << 20));      // 4 MiB
  unsigned short* Vb  = (unsigned short*)(ws + (56u << 20));      // 4 MiB
  unsigned short* Vtb = (unsigned short*)(ws + (60u << 20));      // 4 MiB
  unsigned short* AO  = (unsigned short*)(ws + (64u << 20));      // 16 MiB
  float* ct = (float*)(ws + (80u << 20));                         // 256 KiB
  float* st = (float*)(ws + (81u << 20));                         // 256 KiB

  conv_all<<<18688, 256, 0, stream>>>(x, Wq, Wk, Wv, Wo, xb, Wqb, Wkb, Wvb, Wob, ct, st);

  gemm_qkv256<<<192, 512, 0, stream>>>(xb, Wqb, Wkb, Wvb, Qb, Kb, Vb, ct, st);
  transpose_v<<<512, 256, 0, stream>>>(Vb, Vtb);

  attn_fwd<<<1024, 256, 0, stream>>>(Qb, Kb, Vtb, AO);

  gemm_out128<<<256, 512, 0, stream>>>(AO, Wob, (float*)d_out);
}

// Round 7
// 207.390 us; speedup vs baseline: 1.0255x; 1.0255x over previous
//
#include <hip/hip_runtime.h>
#include <math.h>

#define BATCHN 2
#define SEQ 2048
#define DMODEL 2048
#define NH 32
#define NKV 8
#define HDIM 64
#define KVD 512          // NKV*HDIM
#define ROWS 4096        // BATCHN*SEQ

typedef __bf16 bf16x8 __attribute__((ext_vector_type(8)));
typedef float f32x4 __attribute__((ext_vector_type(4)));
typedef unsigned short u16x8 __attribute__((ext_vector_type(8)));

#define MFMA(a, b, c) __builtin_amdgcn_mfma_f32_16x16x32_bf16(a, b, c, 0, 0, 0)

__device__ __forceinline__ unsigned short f2bf(float f) {
  union { float f; unsigned u; } v; v.f = f;
  unsigned u = v.u;
  u += 0x7fffu + ((u >> 16) & 1u);   // RNE
  return (unsigned short)(u >> 16);
}

__device__ __forceinline__ unsigned cvtpk(float a, float b) {
  unsigned r;
  asm("v_cvt_pk_bf16_f32 %0, %1, %2" : "=v"(r) : "v"(a), "v"(b));
  return r;
}
__device__ __forceinline__ void pl32(unsigned& a, unsigned& b) {
  asm("v_permlane32_swap_b32 %0, %1" : "+v"(a), "+v"(b));
}
__device__ __forceinline__ void pl16(unsigned& a, unsigned& b) {
  asm("v_permlane16_swap_b32 %0, %1" : "+v"(a), "+v"(b));
}
__device__ __forceinline__ float exp2v(float x) {
  float r;
  asm("v_exp_f32 %0, %1" : "=v"(r) : "v"(x));
  return r;
}

// async global->LDS, 16B per lane; LDS dest = wave-uniform base + lane*16 (HW rule)
__device__ __forceinline__ void gload16(const void* g, void* l) {
  __builtin_amdgcn_global_load_lds((const __attribute__((address_space(1))) unsigned int*)g,
                                   (__attribute__((address_space(3))) unsigned int*)l, 16, 0, 0);
}

#define FENCE() asm volatile("" ::: "memory")
#define BARRIER() do { FENCE(); __builtin_amdgcn_s_barrier(); FENCE(); } while (0)
#define LGKM0() asm volatile("s_waitcnt lgkmcnt(0)" ::: "memory")
#define VMCNT(n) asm volatile("s_waitcnt vmcnt(" #n ")" ::: "memory")

// ---------------- fused fp32->bf16 conversions + RoPE tables (one launch) ----------------
__global__ __launch_bounds__(256) void conv_all(const float* __restrict__ x,
                                                const float* __restrict__ Wq,
                                                const float* __restrict__ Wk,
                                                const float* __restrict__ Wv,
                                                const float* __restrict__ Wo,
                                                unsigned short* __restrict__ xb,
                                                unsigned short* __restrict__ Wqb,
                                                unsigned short* __restrict__ Wkb,
                                                unsigned short* __restrict__ Wvb,
                                                unsigned short* __restrict__ Wob,
                                                float* __restrict__ ct,
                                                float* __restrict__ st) {
  int i = blockIdx.x * 256 + threadIdx.x;
  const float* in;
  unsigned short* out;
  int off;
  if (i < 2097152)      { in = x;  out = xb;  off = i; }
  else if (i < 3145728) { in = Wq; out = Wqb; off = i - 2097152; }
  else if (i < 3407872) { in = Wk; out = Wkb; off = i - 3145728; }
  else if (i < 3670016) { in = Wv; out = Wvb; off = i - 3407872; }
  else if (i < 4718592) { in = Wo; out = Wob; off = i - 3670016; }
  else {
    int t = i - 4718592;  // 0..65535 : RoPE tables [SEQ][32]
    int s = t >> 5, f = t & 31;
    float inv = __expf(-(float)f * (9.210340371976184f / 32.0f));  // 10000^(-f/32)
    float ang = (float)s * inv;
    ct[t] = cosf(ang);
    st[t] = sinf(ang);
    return;
  }
  float4 v = ((const float4*)in)[off];
  ushort4 o;
  o.x = f2bf(v.x); o.y = f2bf(v.y); o.z = f2bf(v.z); o.w = f2bf(v.w);
  ((ushort4*)out)[off] = o;
}

// ================= QKV GEMM: 256x256 tile, BK=64, 8 waves, 4-phase =================
// Staging quanta = 64-row sweeps (1 gload each). Deadlines: p0 needs A[*][0]+B[*][*],
// p2 needs A[*][1]. Ledger: at (T,p0) stage [A00,A10,B*4](T+1); at (T,p2) stage [A01,A11](T+1).
// Waits (pre-barrier, cross-wave): end-p1 vmcnt(6) drains A-sweep1(T); end-p3 vmcnt(2)
// drains the six p0-deadline loads of T+1. All staged >=2-3 phases before read.
__global__ __launch_bounds__(512) void gemm_qkv256(const unsigned short* __restrict__ A,
                                                   const unsigned short* __restrict__ Bq,
                                                   const unsigned short* __restrict__ Bk,
                                                   const unsigned short* __restrict__ Bv,
                                                   unsigned short* __restrict__ Qo,
                                                   unsigned short* __restrict__ Ko,
                                                   unsigned short* __restrict__ Vo,
                                                   const float* __restrict__ ct,
                                                   const float* __restrict__ st) {
  __shared__ __align__(16) unsigned short Als[2][2][8192];   // [buf][half][128*64]
  __shared__ __align__(16) unsigned short Bls[2][2][8192];
  const int tid = threadIdx.x, lane = tid & 63, wv = tid >> 6;
  const int wm = wv >> 2, wn = wv & 3;
  const int g = lane >> 4, r15 = lane & 15;
  // 192 blocks; XCD chunks of 24, bm-major (bn fastest)
  const int wgid = (blockIdx.x & 7) * 24 + (blockIdx.x >> 3);
  const int bm = wgid / 12, bn = wgid % 12;
  const int row0 = bm << 8;
  const unsigned short* Bp;
  unsigned short* Outb;
  int col0, ldo, rope, qsc;
  if (bn < 8)       { Bp = Bq; Outb = Qo; col0 = bn << 8;        ldo = DMODEL; rope = 1; qsc = 1; }
  else if (bn < 10) { Bp = Bk; Outb = Ko; col0 = (bn - 8) << 8;  ldo = KVD;    rope = 1; qsc = 0; }
  else              { Bp = Bv; Outb = Vo; col0 = (bn - 10) << 8; ldo = KVD;    rope = 0; qsc = 0; }
  const int srl = tid >> 3;
  const int sgc = ((tid & 7) ^ (srl & 7)) << 3;  // pre-swizzled short col
  const unsigned short* gA = A + (size_t)(row0 + srl) * DMODEL + sgc;
  const unsigned short* gB = Bp + (size_t)(col0 + srl) * DMODEL + sgc;

  f32x4 acc[8][4];
#pragma unroll
  for (int i = 0; i < 8; ++i)
#pragma unroll
    for (int jj = 0; jj < 4; ++jj) acc[i][jj] = (f32x4){0.f, 0.f, 0.f, 0.f};

#define STG_AS(buf, h, s, kt) gload16(gA + (size_t)((h) * 128 + (s) * 64) * DMODEL + (kt) * 64, \
                                      &Als[buf][h][(s) * 4096 + (wv << 9)])
#define STG_BS(buf, h, s, kt) gload16(gB + (size_t)((h) * 128 + (s) * 64) * DMODEL + (kt) * 64, \
                                      &Bls[buf][h][(s) * 4096 + (wv << 9)])
#define RA(buf, mf, kk) (*(const bf16x8*)&Als[buf][wm][((mf) * 16 + r15) * 64 + \
                          (((((kk) << 2) + g) ^ (r15 & 7)) << 3)])
#define RB(buf, nf, kk) (*(const bf16x8*)&Bls[buf][wn >> 1][((wn & 1) * 64 + (nf) * 16 + r15) * 64 + \
                          (((((kk) << 2) + g) ^ (r15 & 7)) << 3)])

  // prologue: [A00,A10,B*4](0) then [A01,A11](0); leave A-sweep1 in flight
  STG_AS(0, 0, 0, 0); STG_AS(0, 1, 0, 0);
  STG_BS(0, 0, 0, 0); STG_BS(0, 0, 1, 0); STG_BS(0, 1, 0, 0); STG_BS(0, 1, 1, 0);
  STG_AS(0, 0, 1, 0); STG_AS(0, 1, 1, 0);
  VMCNT(2);
  BARRIER();

  const int NT = DMODEL / 64;  // 32
  for (int t = 0; t < NT; ++t) {
    const int cur = t & 1, nxt = cur ^ 1;
    // ---- phase 0: read A-sweep0 + B lower; stage 6 p0-deadline gloads of T+1 ----
    bf16x8 a0[4][2], b0[2][2];
#pragma unroll
    for (int mf = 0; mf < 4; ++mf) { a0[mf][0] = RA(cur, mf, 0); a0[mf][1] = RA(cur, mf, 1); }
#pragma unroll
    for (int nf = 0; nf < 2; ++nf) { b0[nf][0] = RB(cur, nf, 0); b0[nf][1] = RB(cur, nf, 1); }
    if (t + 1 < NT) {
      STG_AS(nxt, 0, 0, t + 1); STG_AS(nxt, 1, 0, t + 1);
      STG_BS(nxt, 0, 0, t + 1); STG_BS(nxt, 0, 1, t + 1);
      STG_BS(nxt, 1, 0, t + 1); STG_BS(nxt, 1, 1, t + 1);
    }
    BARRIER(); LGKM0();
    __builtin_amdgcn_s_setprio(1);
#pragma unroll
    for (int mf = 0; mf < 4; ++mf)
#pragma unroll
      for (int nf = 0; nf < 2; ++nf) {
        acc[mf][nf] = MFMA(a0[mf][0], b0[nf][0], acc[mf][nf]);
        acc[mf][nf] = MFMA(a0[mf][1], b0[nf][1], acc[mf][nf]);
      }
    __builtin_amdgcn_s_setprio(0);
    BARRIER();
    // ---- phase 1: read B upper; MFMA q1; drain A-sweep1(T) ----
    bf16x8 b2[2][2];
#pragma unroll
    for (int nf = 0; nf < 2; ++nf) { b2[nf][0] = RB(cur, 2 + nf, 0); b2[nf][1] = RB(cur, 2 + nf, 1); }
    BARRIER(); LGKM0();
    __builtin_amdgcn_s_setprio(1);
#pragma unroll
    for (int mf = 0; mf < 4; ++mf)
#pragma unroll
      for (int nf = 0; nf < 2; ++nf) {
        acc[mf][2 + nf] = MFMA(a0[mf][0], b2[nf][0], acc[mf][2 + nf]);
        acc[mf][2 + nf] = MFMA(a0[mf][1], b2[nf][1], acc[mf][2 + nf]);
      }
    __builtin_amdgcn_s_setprio(0);
    if (t < NT - 1) { VMCNT(6); } else { VMCNT(0); }
    BARRIER();
    // ---- phase 2: read A-sweep1; stage [A01,A11](T+1); MFMA q3 ----
    bf16x8 a4[4][2];
#pragma unroll
    for (int mf = 0; mf < 4; ++mf) { a4[mf][0] = RA(cur, 4 + mf, 0); a4[mf][1] = RA(cur, 4 + mf, 1); }
    if (t + 1 < NT) { STG_AS(nxt, 0, 1, t + 1); STG_AS(nxt, 1, 1, t + 1); }
    BARRIER(); LGKM0();
    __builtin_amdgcn_s_setprio(1);
#pragma unroll
    for (int mf = 0; mf < 4; ++mf)
#pragma unroll
      for (int nf = 0; nf < 2; ++nf) {
        acc[4 + mf][2 + nf] = MFMA(a4[mf][0], b2[nf][0], acc[4 + mf][2 + nf]);
        acc[4 + mf][2 + nf] = MFMA(a4[mf][1], b2[nf][1], acc[4 + mf][2 + nf]);
      }
    __builtin_amdgcn_s_setprio(0);
    BARRIER();
    // ---- phase 3: MFMA q2 (held regs); drain T+1's six p0-deadline loads ----
    __builtin_amdgcn_s_setprio(1);
#pragma unroll
    for (int mf = 0; mf < 4; ++mf)
#pragma unroll
      for (int nf = 0; nf < 2; ++nf) {
        acc[4 + mf][nf] = MFMA(a4[mf][0], b0[nf][0], acc[4 + mf][nf]);
        acc[4 + mf][nf] = MFMA(a4[mf][1], b0[nf][1], acc[4 + mf][nf]);
      }
    __builtin_amdgcn_s_setprio(0);
    if (t < NT - 1) { VMCNT(2); }
    BARRIER();
  }
#undef STG_AS
#undef STG_BS
#undef RA
#undef RB

  const float QS = 0.18033688011112042f;  // 0.125 * log2(e)
#pragma unroll
  for (int mf = 0; mf < 8; ++mf) {
#pragma unroll
    for (int rr = 0; rr < 4; ++rr) {
      const int m = row0 + (wm << 7) + (mf << 4) + (g << 2) + rr;
      const float* ctr = ct + ((m & (SEQ - 1)) << 5);
      const float* str = st + ((m & (SEQ - 1)) << 5);
#pragma unroll
      for (int nf = 0; nf < 4; ++nf) {
        const int n = col0 + (wn << 6) + (nf << 4) + r15;
        float v = acc[mf][nf][rr];
        float p = __shfl_xor(v, 1);
        if (rope) {
          int fi = (n & 63) >> 1;
          float c = ctr[fi], sn = str[fi];
          v = (lane & 1) ? (p * sn + v * c) : (v * c - p * sn);
        }
        if (qsc) v *= QS;
        Outb[(size_t)m * ldo + n] = f2bf(v);
      }
    }
  }
}

// ================= out-proj GEMM: 128x256 tile, BK=64, 8 waves, 2-phase, TRIPLE buffer =================
// All 6 gloads of a tile have p0 deadlines -> 2-buffer depth maxes at 2 phases; with 3 buffers
// tile T+2 is staged at (T,p0/p1) -> 3-4 phase depth. end-p1 vmcnt(6) drains tile T+1's loads.
__global__ __launch_bounds__(512) void gemm_out128(const unsigned short* __restrict__ A,
                                                   const unsigned short* __restrict__ B,
                                                   float* __restrict__ C) {
  __shared__ __align__(16) unsigned short Als[3][8192];      // [buf][128*64]
  __shared__ __align__(16) unsigned short Bls[3][2][8192];   // [buf][half][128*64]
  const int tid = threadIdx.x, lane = tid & 63, wv = tid >> 6;
  const int wm = wv >> 2, wn = wv & 3;
  const int g = lane >> 4, r15 = lane & 15;
  const int wgid = (blockIdx.x & 7) * 32 + (blockIdx.x >> 3);
  const int bm = wgid >> 3, bn = wgid & 7;
  const int row0 = bm << 7, col0 = bn << 8;
  const int srl = tid >> 3;
  const int sgc = ((tid & 7) ^ (srl & 7)) << 3;
  const unsigned short* gA = A + (size_t)(row0 + srl) * DMODEL + sgc;
  const unsigned short* gB = B + (size_t)(col0 + srl) * DMODEL + sgc;

  f32x4 acc[4][4];
#pragma unroll
  for (int i = 0; i < 4; ++i)
#pragma unroll
    for (int jj = 0; jj < 4; ++jj) acc[i][jj] = (f32x4){0.f, 0.f, 0.f, 0.f};

#define STG_A1(buf, kt) do { \
    gload16(gA + (size_t)(kt) * 64, &Als[buf][(wv << 9)]); \
    gload16(gA + (size_t)64 * DMODEL + (size_t)(kt) * 64, &Als[buf][4096 + (wv << 9)]); } while (0)
#define STG_B1(buf, h, kt) do { \
    gload16(gB + (size_t)((h) * 128) * DMODEL + (kt) * 64, &Bls[buf][h][(wv << 9)]); \
    gload16(gB + (size_t)((h) * 128 + 64) * DMODEL + (kt) * 64, &Bls[buf][h][4096 + (wv << 9)]); } while (0)
#define RA1(buf, mf, kk) (*(const bf16x8*)&Als[buf][((wm << 6) + (mf) * 16 + r15) * 64 + \
                           (((((kk) << 2) + g) ^ (r15 & 7)) << 3)])
#define RB1(buf, nf, kk) (*(const bf16x8*)&Bls[buf][wn >> 1][((wn & 1) * 64 + (nf) * 16 + r15) * 64 + \
                           (((((kk) << 2) + g) ^ (r15 & 7)) << 3)])

  // prologue: B(0),A(0),B(1),A(1); leave tile1's 6 loads in flight
  STG_B1(0, 0, 0); STG_B1(0, 1, 0); STG_A1(0, 0);
  STG_B1(1, 0, 1); STG_B1(1, 1, 1); STG_A1(1, 1);
  VMCNT(6);
  BARRIER();

  const int NT = DMODEL / 64;  // 32
  for (int t = 0; t < NT; ++t) {
    const int cur = t % 3;
    const int stg = (t + 2) % 3;
    // ---- phase 0: read A + B lower; stage B(T+2); MFMA left ----
    bf16x8 a[4][2], b0[2][2];
#pragma unroll
    for (int mf = 0; mf < 4; ++mf) { a[mf][0] = RA1(cur, mf, 0); a[mf][1] = RA1(cur, mf, 1); }
#pragma unroll
    for (int nf = 0; nf < 2; ++nf) { b0[nf][0] = RB1(cur, nf, 0); b0[nf][1] = RB1(cur, nf, 1); }
    if (t + 2 < NT) { STG_B1(stg, 0, t + 2); STG_B1(stg, 1, t + 2); }
    BARRIER(); LGKM0();
    __builtin_amdgcn_s_setprio(1);
#pragma unroll
    for (int mf = 0; mf < 4; ++mf)
#pragma unroll
      for (int nf = 0; nf < 2; ++nf) {
        acc[mf][nf] = MFMA(a[mf][0], b0[nf][0], acc[mf][nf]);
        acc[mf][nf] = MFMA(a[mf][1], b0[nf][1], acc[mf][nf]);
      }
    __builtin_amdgcn_s_setprio(0);
    BARRIER();
    // ---- phase 1: read B upper; stage A(T+2); MFMA right; drain tile T+1 ----
    bf16x8 b2[2][2];
#pragma unroll
    for (int nf = 0; nf < 2; ++nf) { b2[nf][0] = RB1(cur, 2 + nf, 0); b2[nf][1] = RB1(cur, 2 + nf, 1); }
    if (t + 2 < NT) STG_A1(stg, t + 2);
    BARRIER(); LGKM0();
    __builtin_amdgcn_s_setprio(1);
#pragma unroll
    for (int mf = 0; mf < 4; ++mf)
#pragma unroll
      for (int nf = 0; nf < 2; ++nf) {
        acc[mf][2 + nf] = MFMA(a[mf][0], b2[nf][0], acc[mf][2 + nf]);
        acc[mf][2 + nf] = MFMA(a[mf][1], b2[nf][1], acc[mf][2 + nf]);
      }
    __builtin_amdgcn_s_setprio(0);
    if (t + 2 < NT) { VMCNT(6); }
    else if (t + 2 == NT) { VMCNT(0); }
    BARRIER();
  }
#undef STG_A1
#undef STG_B1
#undef RA1
#undef RB1

#pragma unroll
  for (int mf = 0; mf < 4; ++mf)
#pragma unroll
    for (int rr = 0; rr < 4; ++rr) {
      const int m = row0 + (wm << 6) + (mf << 4) + (g << 2) + rr;
#pragma unroll
      for (int nf = 0; nf < 4; ++nf)
        C[(size_t)m * DMODEL + col0 + (wn << 6) + (nf << 4) + r15] = acc[mf][nf][rr];
    }
}

// ---------------- V transpose via LDS tile: (B*S, KVD) -> (B, NKV, HDIM, S) ----------------
__global__ __launch_bounds__(256) void transpose_v(const unsigned short* __restrict__ V,
                                                   unsigned short* __restrict__ Vt) {
  __shared__ unsigned short t[64][80];
  const int bid = blockIdx.x;       // 512 = 2*8*32
  const int st_ = bid & 31;
  const int kvh = (bid >> 5) & 7;
  const int b = bid >> 8;
  const int tid = threadIdx.x;
#pragma unroll
  for (int p = 0; p < 2; ++p) {
    int idx = p * 2048 + tid * 8;
    int r = idx >> 6, c = idx & 63;
    u16x8 v = *(const u16x8*)(V + (size_t)(b * SEQ + st_ * 64 + r) * KVD + kvh * 64 + c);
#pragma unroll
    for (int jj = 0; jj < 8; ++jj) t[c + jj][r] = v[jj];
  }
  __syncthreads();
#pragma unroll
  for (int p = 0; p < 2; ++p) {
    int idx = p * 2048 + tid * 8;
    int d = idx >> 6, s = idx & 63;
    u16x8 v = *(const u16x8*)&t[d][s];
    *(u16x8*)(Vt + (size_t)((b * NKV + kvh) * HDIM + d) * SEQ + st_ * 64 + s) = v;
  }
}

// ---------------- Flash attention (causal, GQA) ----------------
__global__ __launch_bounds__(256) void attn_fwd(const unsigned short* __restrict__ Q,
                                                const unsigned short* __restrict__ K,
                                                const unsigned short* __restrict__ Vt,
                                                unsigned short* __restrict__ O) {
  __shared__ __align__(16) unsigned short Kls[2][64 * 64];
  __shared__ __align__(16) unsigned short Vls[2][64 * 64];
  const int bid = blockIdx.x;
  const int xcd = bid & 7;
  const int within = bid >> 3;             // 0..127
  const int grp = xcd * 2 + (within >> 6); // 0..15 = (b,kvh)
  const int w64 = within & 63;
  const int j = w64 & 15;                  // pair: tiles j and 31-j
  const int hsub = w64 >> 4;
  const int b = grp >> 3, kvh = grp & 7;
  const int h = kvh * 4 + hsub;
  const int wave = threadIdx.x >> 6, lane = threadIdx.x & 63;
  const int g = lane >> 4, r15 = lane & 15;
  const int sr = lane >> 3;
  const int sc = (((lane & 7) << 4) ^ (sr << 4)) >> 1;  // pre-swizzled src col (shorts)
  const unsigned short* kbase = K + (size_t)b * SEQ * KVD + kvh * HDIM;
  const unsigned short* vbase = Vt + (size_t)((b * NKV + kvh) * HDIM) * SEQ;

  union { u16x8 s; bf16x8 v; } one8;
#pragma unroll
  for (int z = 0; z < 8; ++z) one8.s[z] = 0x3F80;  // bf16 1.0

  auto STAGE = [&](int bi, int kbv) {
#pragma unroll
    for (int i = 0; i < 2; ++i) {
      const int r = wave * 16 + i * 8;
      gload16(kbase + (size_t)(kbv + r + sr) * KVD + sc, &Kls[bi][r * 64]);
      gload16(vbase + (size_t)(r + sr) * SEQ + kbv + sc, &Vls[bi][r * 64]);
    }
  };

#pragma unroll 1
  for (int sel = 0; sel < 2; ++sel) {
    const int qt = sel ? (31 - j) : j;
    const int qrow0 = qt * 64 + wave * 16;
    const unsigned short* qp = Q + (size_t)(b * SEQ + qrow0 + r15) * DMODEL + h * HDIM;
    bf16x8 q0 = *(const bf16x8*)(qp + g * 8);
    bf16x8 q1 = *(const bf16x8*)(qp + 32 + g * 8);
    f32x4 oacc[4] = {};
    f32x4 lacc = {};
    const int kend = (qt + 1) * 64;
    __syncthreads();           // prior-tile reads drained before restaging
    STAGE(0, 0);
    int buf = 0;
    for (int kb = 0; kb < kend; kb += 64) {
      __syncthreads();         // staged loads for buf complete; buf^1 reads done
      if (kb + 64 < kend) STAGE(buf ^ 1, kb + 64);
      const char* Kc = (const char*)&Kls[buf][0];
      const char* Vc = (const char*)&Vls[buf][0];
      f32x4 s[4];
      __builtin_amdgcn_s_setprio(1);
#pragma unroll
      for (int f = 0; f < 4; ++f) {
        const int r = f * 16 + r15;
        const int sw = (r & 7) << 4;
        bf16x8 k0 = *(const bf16x8*)(Kc + r * 128 + ((g * 16) ^ sw));
        bf16x8 k1 = *(const bf16x8*)(Kc + r * 128 + ((64 + g * 16) ^ sw));
        f32x4 z = {};
        s[f] = MFMA(k1, q1, MFMA(k0, q0, z));
      }
      __builtin_amdgcn_s_setprio(0);
      if (kb + 64 == kend) {   // diagonal tile: causal mask
        const int q = qrow0 + r15;
#pragma unroll
        for (int f = 0; f < 4; ++f)
#pragma unroll
          for (int rr = 0; rr < 4; ++rr)
            if (kb + f * 16 + g * 4 + rr > q) s[f][rr] = -1e30f;
      }
#pragma unroll
      for (int f = 0; f < 4; ++f)
#pragma unroll
        for (int rr = 0; rr < 4; ++rr) s[f][rr] = exp2v(s[f][rr]);
      // C-layout -> A-layout in-register (cvt_pk + permlane swaps)
      bf16x8 p1, p2;
      {
        union { bf16x8 v; unsigned u[4]; } P1, P2;
        unsigned a0 = cvtpk(s[0][0], s[0][1]), b0 = cvtpk(s[1][0], s[1][1]);
        pl32(a0, b0); pl16(a0, b0);
        unsigned a1 = cvtpk(s[0][2], s[0][3]), b1 = cvtpk(s[1][2], s[1][3]);
        pl32(a1, b1); pl16(a1, b1);
        P1.u[0] = a0; P1.u[1] = a1; P1.u[2] = b0; P1.u[3] = b1;
        unsigned a2 = cvtpk(s[2][0], s[2][1]), b2 = cvtpk(s[3][0], s[3][1]);
        pl32(a2, b2); pl16(a2, b2);
        unsigned a3 = cvtpk(s[2][2], s[2][3]), b3 = cvtpk(s[3][2], s[3][3]);
        pl32(a3, b3); pl16(a3, b3);
        P2.u[0] = a2; P2.u[1] = a3; P2.u[2] = b2; P2.u[3] = b3;
        p1 = P1.v; p2 = P2.v;
      }
      // l[q] accumulated on MFMA pipe: D rows (g*4+rr) = q, cols identical
      lacc = MFMA(p2, one8.v, MFMA(p1, one8.v, lacc));
      __builtin_amdgcn_s_setprio(1);
#pragma unroll
      for (int dc = 0; dc < 4; ++dc) {
        const int r = dc * 16 + r15;
        const int sw = (r & 7) << 4;
        bf16x8 v0 = *(const bf16x8*)(Vc + r * 128 + ((g * 16) ^ sw));
        bf16x8 v1 = *(const bf16x8*)(Vc + r * 128 + ((64 + g * 16) ^ sw));
        oacc[dc] = MFMA(p2, v1, MFMA(p1, v0, oacc[dc]));
      }
      __builtin_amdgcn_s_setprio(0);
      buf ^= 1;
    }
    float rls[4];
#pragma unroll
    for (int rr = 0; rr < 4; ++rr) rls[rr] = 1.0f / lacc[rr];
    unsigned short* optr = O + (size_t)(b * SEQ + qrow0) * DMODEL + h * HDIM;
#pragma unroll
    for (int dc = 0; dc < 4; ++dc)
#pragma unroll
      for (int rr = 0; rr < 4; ++rr)
        optr[(size_t)(g * 4 + rr) * DMODEL + dc * 16 + r15] = f2bf(oacc[dc][rr] * rls[rr]);
  }
}

extern "C" void kernel_launch(void* const* d_in, const int* in_sizes, int n_in,
                              void* d_out, int out_size, void* d_ws, size_t ws_size,
                              hipStream_t stream) {
  const float* x  = (const float*)d_in[0];
  const float* Wq = (const float*)d_in[1];
  const float* Wk = (const float*)d_in[2];
  const float* Wv = (const float*)d_in[3];
  const float* Wo = (const float*)d_in[4];

  char* ws = (char*)d_ws;
  unsigned short* xb  = (unsigned short*)(ws);                    // 16 MiB
  unsigned short* Wqb = (unsigned short*)(ws + (16u << 20));      // 8 MiB
  unsigned short* Wkb = (unsigned short*)(ws + (24u << 20));      // 2 MiB
  unsigned short* Wvb = (unsigned short*)(ws + (26u << 20));      // 2 MiB
  unsigned short* Wob = (unsigned short*)(ws + (28u << 20));      // 8 MiB
  unsigned short* Qb  = (unsigned short*)(ws + (36u << 20));      // 16 MiB
  unsigned short* Kb  = (unsigned short*)(ws + (52u << 20));      // 4 MiB
  unsigned short* Vb  = (unsigned short*)(ws + (56u << 20));      // 4 MiB
  unsigned short* Vtb = (unsigned short*)(ws + (60u << 20));      // 4 MiB
  unsigned short* AO  = (unsigned short*)(ws + (64u << 20));      // 16 MiB
  float* ct = (float*)(ws + (80u << 20));                         // 256 KiB
  float* st = (float*)(ws + (81u << 20));                         // 256 KiB

  conv_all<<<18688, 256, 0, stream>>>(x, Wq, Wk, Wv, Wo, xb, Wqb, Wkb, Wvb, Wob, ct, st);

  gemm_qkv256<<<192, 512, 0, stream>>>(xb, Wqb, Wkb, Wvb, Qb, Kb, Vb, ct, st);
  transpose_v<<<512, 256, 0, stream>>>(Vb, Vtb);

  attn_fwd<<<1024, 256, 0, stream>>>(Qb, Kb, Vtb, AO);

  gemm_out128<<<256, 512, 0, stream>>>(AO, Wob, (float*)d_out);
}

// Round 8
// 200.238 us; speedup vs baseline: 1.0621x; 1.0357x over previous
//
#include <hip/hip_runtime.h>
#include <math.h>

#define BATCHN 2
#define SEQ 2048
#define DMODEL 2048
#define NH 32
#define NKV 8
#define HDIM 64
#define KVD 512          // NKV*HDIM
#define ROWS 4096        // BATCHN*SEQ

typedef __bf16 bf16x8 __attribute__((ext_vector_type(8)));
typedef float f32x4 __attribute__((ext_vector_type(4)));
typedef unsigned short u16x8 __attribute__((ext_vector_type(8)));

#define MFMA(a, b, c) __builtin_amdgcn_mfma_f32_16x16x32_bf16(a, b, c, 0, 0, 0)

__device__ __forceinline__ unsigned short f2bf(float f) {
  union { float f; unsigned u; } v; v.f = f;
  unsigned u = v.u;
  u += 0x7fffu + ((u >> 16) & 1u);   // RNE
  return (unsigned short)(u >> 16);
}

__device__ __forceinline__ unsigned cvtpk(float a, float b) {
  unsigned r;
  asm("v_cvt_pk_bf16_f32 %0, %1, %2" : "=v"(r) : "v"(a), "v"(b));
  return r;
}
__device__ __forceinline__ void pl32(unsigned& a, unsigned& b) {
  asm("v_permlane32_swap_b32 %0, %1" : "+v"(a), "+v"(b));
}
__device__ __forceinline__ void pl16(unsigned& a, unsigned& b) {
  asm("v_permlane16_swap_b32 %0, %1" : "+v"(a), "+v"(b));
}
__device__ __forceinline__ float exp2v(float x) {
  float r;
  asm("v_exp_f32 %0, %1" : "=v"(r) : "v"(x));
  return r;
}

// async global->LDS, 16B per lane; LDS dest = wave-uniform base + lane*16 (HW rule)
__device__ __forceinline__ void gload16(const void* g, void* l) {
  __builtin_amdgcn_global_load_lds((const __attribute__((address_space(1))) unsigned int*)g,
                                   (__attribute__((address_space(3))) unsigned int*)l, 16, 0, 0);
}

#define FENCE() asm volatile("" ::: "memory")
#define BARRIER() do { FENCE(); __builtin_amdgcn_s_barrier(); FENCE(); } while (0)
#define LGKM0() asm volatile("s_waitcnt lgkmcnt(0)" ::: "memory")
#define VMCNT(n) asm volatile("s_waitcnt vmcnt(" #n ")" ::: "memory")

// ---------------- fused fp32->bf16 conversions + RoPE tables (one launch) ----------------
__global__ __launch_bounds__(256) void conv_all(const float* __restrict__ x,
                                                const float* __restrict__ Wq,
                                                const float* __restrict__ Wk,
                                                const float* __restrict__ Wv,
                                                const float* __restrict__ Wo,
                                                unsigned short* __restrict__ xb,
                                                unsigned short* __restrict__ Wqb,
                                                unsigned short* __restrict__ Wkb,
                                                unsigned short* __restrict__ Wvb,
                                                unsigned short* __restrict__ Wob,
                                                float* __restrict__ ct,
                                                float* __restrict__ st) {
  int i = blockIdx.x * 256 + threadIdx.x;
  const float* in;
  unsigned short* out;
  int off;
  if (i < 2097152)      { in = x;  out = xb;  off = i; }
  else if (i < 3145728) { in = Wq; out = Wqb; off = i - 2097152; }
  else if (i < 3407872) { in = Wk; out = Wkb; off = i - 3145728; }
  else if (i < 3670016) { in = Wv; out = Wvb; off = i - 3407872; }
  else if (i < 4718592) { in = Wo; out = Wob; off = i - 3670016; }
  else {
    int t = i - 4718592;  // 0..65535 : RoPE tables [SEQ][32]
    int s = t >> 5, f = t & 31;
    float inv = __expf(-(float)f * (9.210340371976184f / 32.0f));  // 10000^(-f/32)
    float ang = (float)s * inv;
    ct[t] = cosf(ang);
    st[t] = sinf(ang);
    return;
  }
  float4 v = ((const float4*)in)[off];
  ushort4 o;
  o.x = f2bf(v.x); o.y = f2bf(v.y); o.z = f2bf(v.z); o.w = f2bf(v.w);
  ((ushort4*)out)[off] = o;
}

// ================= QKV GEMM (round-5 structure): 128x128 tile, BK=64, 8 waves =================
// 2 phases/K-tile x 8 MFMA; double-buffered swizzled LDS; counted vmcnt; setprio.
// Block mapping: XCD chunks of 96, bn-FASTEST within chunk -> 4 A-panels (2MB) L2-resident,
// 24 B-panels stream shared across XCDs via L3.
__global__ __launch_bounds__(512, 4) void gemm_qkv8p(const unsigned short* __restrict__ A,
                                                     const unsigned short* __restrict__ Bq,
                                                     const unsigned short* __restrict__ Bk,
                                                     const unsigned short* __restrict__ Bv,
                                                     unsigned short* __restrict__ Qo,
                                                     unsigned short* __restrict__ Ko,
                                                     unsigned short* __restrict__ Vo,
                                                     const float* __restrict__ ct,
                                                     const float* __restrict__ st) {
  __shared__ __align__(16) unsigned short Als[2][128 * 64];
  __shared__ __align__(16) unsigned short Bls[2][128 * 64];
  const int tid = threadIdx.x;
  const int lane = tid & 63, wv = tid >> 6;   // 8 waves
  const int wm = wv >> 2, wn = wv & 3;        // 2 x 4
  const int g = lane >> 4, r15 = lane & 15;
  // XCD-chunked, bn-fastest: chunk = 96 blocks = 4 bm x 24 bn
  const int wgid = (blockIdx.x & 7) * 96 + (blockIdx.x >> 3);
  const int bm = wgid / 24, bn = wgid % 24;
  const int row0 = bm << 7;
  const unsigned short* Bp;
  unsigned short* Outb;
  int col0, ldo, rope, qsc;
  if (bn < 16)      { Bp = Bq; Outb = Qo; col0 = bn << 7;        ldo = DMODEL; rope = 1; qsc = 1; }
  else if (bn < 20) { Bp = Bk; Outb = Ko; col0 = (bn - 16) << 7; ldo = KVD;    rope = 1; qsc = 0; }
  else              { Bp = Bv; Outb = Vo; col0 = (bn - 20) << 7; ldo = KVD;    rope = 0; qsc = 0; }
  const int srow = (wv << 3) + ((lane >> 3) & 7);                 // 0..63
  const int scol = (((lane & 7) ^ ((lane >> 3) & 7)) << 3);       // pre-swizzled short col
  const unsigned short* gA = A + (size_t)(row0 + srow) * DMODEL + scol;
  const unsigned short* gB = Bp + (size_t)(col0 + srow) * DMODEL + scol;
  const int ldsoff = (wv << 9);

  f32x4 acc[4][2];
#pragma unroll
  for (int i = 0; i < 4; ++i) { acc[i][0] = (f32x4){0,0,0,0}; acc[i][1] = (f32x4){0,0,0,0}; }

#define STAGE_A(buf, t, j) gload16(gA + (size_t)((t) * 64) + (size_t)((j) * 64) * DMODEL, \
                                   &Als[buf][(j) * 4096 + ldsoff])
#define STAGE_B(buf, t, j) gload16(gB + (size_t)((t) * 64) + (size_t)((j) * 64) * DMODEL, \
                                   &Bls[buf][(j) * 4096 + ldsoff])
#define RD_A(buf, mf, kk) (*(const bf16x8*)&Als[buf][((wm << 6) + ((mf) << 4) + r15) * 64 + \
                            ((((kk) << 2) + g) ^ (r15 & 7)) * 8])
#define RD_B(buf, nf, kk) (*(const bf16x8*)&Bls[buf][((wn << 5) + ((nf) << 4) + r15) * 64 + \
                            ((((kk) << 2) + g) ^ (r15 & 7)) * 8])

  STAGE_A(0, 0, 0); STAGE_A(0, 0, 1); STAGE_B(0, 0, 0); STAGE_B(0, 0, 1);
  STAGE_A(1, 1, 0); STAGE_A(1, 1, 1); STAGE_B(1, 1, 0); STAGE_B(1, 1, 1);
  VMCNT(4);
  BARRIER();

  const int NT = DMODEL / 64;  // 32
  for (int t = 0; t < NT; ++t) {
    const int cur = t & 1;
    bf16x8 bfr[2][2];
#pragma unroll
    for (int nf = 0; nf < 2; ++nf)
#pragma unroll
      for (int kk = 0; kk < 2; ++kk) bfr[nf][kk] = RD_B(cur, nf, kk);
    bf16x8 a00 = RD_A(cur, 0, 0), a01 = RD_A(cur, 0, 1);
    bf16x8 a10 = RD_A(cur, 1, 0), a11 = RD_A(cur, 1, 1);
    if (t >= 1 && t + 1 < NT) { STAGE_A(cur ^ 1, t + 1, 0); STAGE_A(cur ^ 1, t + 1, 1); }
    BARRIER();
    __builtin_amdgcn_s_setprio(1);
#pragma unroll
    for (int nf = 0; nf < 2; ++nf) {
      acc[0][nf] = MFMA(a00, bfr[nf][0], acc[0][nf]);
      acc[0][nf] = MFMA(a01, bfr[nf][1], acc[0][nf]);
      acc[1][nf] = MFMA(a10, bfr[nf][0], acc[1][nf]);
      acc[1][nf] = MFMA(a11, bfr[nf][1], acc[1][nf]);
    }
    __builtin_amdgcn_s_setprio(0);
    BARRIER();
    bf16x8 a20 = RD_A(cur, 2, 0), a21 = RD_A(cur, 2, 1);
    bf16x8 a30 = RD_A(cur, 3, 0), a31 = RD_A(cur, 3, 1);
    if (t + 2 < NT) { STAGE_B(cur, t + 2, 0); STAGE_B(cur, t + 2, 1); }
    BARRIER();
    __builtin_amdgcn_s_setprio(1);
#pragma unroll
    for (int nf = 0; nf < 2; ++nf) {
      acc[2][nf] = MFMA(a20, bfr[nf][0], acc[2][nf]);
      acc[2][nf] = MFMA(a21, bfr[nf][1], acc[2][nf]);
      acc[3][nf] = MFMA(a30, bfr[nf][0], acc[3][nf]);
      acc[3][nf] = MFMA(a31, bfr[nf][1], acc[3][nf]);
    }
    __builtin_amdgcn_s_setprio(0);
    if (t < NT - 1) {
      if (t == NT - 2) VMCNT(0);
      else             VMCNT(2);
    }
    BARRIER();
  }

  const float QS = 0.18033688011112042f;  // 0.125 * log2(e)
#pragma unroll
  for (int mf = 0; mf < 4; ++mf) {
#pragma unroll
    for (int rr = 0; rr < 4; ++rr) {
      const int m = row0 + (wm << 6) + (mf << 4) + (g << 2) + rr;
      const float* ctr = ct + ((m & (SEQ - 1)) << 5);
      const float* str = st + ((m & (SEQ - 1)) << 5);
#pragma unroll
      for (int nf = 0; nf < 2; ++nf) {
        const int n = col0 + (wn << 5) + (nf << 4) + r15;
        float v = acc[mf][nf][rr];
        float p = __shfl_xor(v, 1);
        if (rope) {
          int fi = (n & 63) >> 1;
          float c = ctr[fi], sn = str[fi];
          v = (lane & 1) ? (p * sn + v * c) : (v * c - p * sn);
        }
        if (qsc) v *= QS;
        Outb[(size_t)m * ldo + n] = f2bf(v);
      }
    }
  }
#undef STAGE_A
#undef STAGE_B
#undef RD_A
#undef RD_B
}

// ================= out-proj GEMM: 128x256 tile, BK=64, 8 waves, 2-phase, TRIPLE buffer =================
__global__ __launch_bounds__(512) void gemm_out128(const unsigned short* __restrict__ A,
                                                   const unsigned short* __restrict__ B,
                                                   float* __restrict__ C) {
  __shared__ __align__(16) unsigned short Als[3][8192];      // [buf][128*64]
  __shared__ __align__(16) unsigned short Bls[3][2][8192];   // [buf][half][128*64]
  const int tid = threadIdx.x, lane = tid & 63, wv = tid >> 6;
  const int wm = wv >> 2, wn = wv & 3;
  const int g = lane >> 4, r15 = lane & 15;
  const int wgid = (blockIdx.x & 7) * 32 + (blockIdx.x >> 3);
  const int bm = wgid >> 3, bn = wgid & 7;
  const int row0 = bm << 7, col0 = bn << 8;
  const int srl = tid >> 3;
  const int sgc = ((tid & 7) ^ (srl & 7)) << 3;
  const unsigned short* gA = A + (size_t)(row0 + srl) * DMODEL + sgc;
  const unsigned short* gB = B + (size_t)(col0 + srl) * DMODEL + sgc;

  f32x4 acc[4][4];
#pragma unroll
  for (int i = 0; i < 4; ++i)
#pragma unroll
    for (int jj = 0; jj < 4; ++jj) acc[i][jj] = (f32x4){0.f, 0.f, 0.f, 0.f};

#define STG_A1(buf, kt) do { \
    gload16(gA + (size_t)(kt) * 64, &Als[buf][(wv << 9)]); \
    gload16(gA + (size_t)64 * DMODEL + (size_t)(kt) * 64, &Als[buf][4096 + (wv << 9)]); } while (0)
#define STG_B1(buf, h, kt) do { \
    gload16(gB + (size_t)((h) * 128) * DMODEL + (kt) * 64, &Bls[buf][h][(wv << 9)]); \
    gload16(gB + (size_t)((h) * 128 + 64) * DMODEL + (kt) * 64, &Bls[buf][h][4096 + (wv << 9)]); } while (0)
#define RA1(buf, mf, kk) (*(const bf16x8*)&Als[buf][((wm << 6) + (mf) * 16 + r15) * 64 + \
                           (((((kk) << 2) + g) ^ (r15 & 7)) << 3)])
#define RB1(buf, nf, kk) (*(const bf16x8*)&Bls[buf][wn >> 1][((wn & 1) * 64 + (nf) * 16 + r15) * 64 + \
                           (((((kk) << 2) + g) ^ (r15 & 7)) << 3)])

  STG_B1(0, 0, 0); STG_B1(0, 1, 0); STG_A1(0, 0);
  STG_B1(1, 0, 1); STG_B1(1, 1, 1); STG_A1(1, 1);
  VMCNT(6);
  BARRIER();

  const int NT = DMODEL / 64;  // 32
  for (int t = 0; t < NT; ++t) {
    const int cur = t % 3;
    const int stg = (t + 2) % 3;
    bf16x8 a[4][2], b0[2][2];
#pragma unroll
    for (int mf = 0; mf < 4; ++mf) { a[mf][0] = RA1(cur, mf, 0); a[mf][1] = RA1(cur, mf, 1); }
#pragma unroll
    for (int nf = 0; nf < 2; ++nf) { b0[nf][0] = RB1(cur, nf, 0); b0[nf][1] = RB1(cur, nf, 1); }
    if (t + 2 < NT) { STG_B1(stg, 0, t + 2); STG_B1(stg, 1, t + 2); }
    BARRIER(); LGKM0();
    __builtin_amdgcn_s_setprio(1);
#pragma unroll
    for (int mf = 0; mf < 4; ++mf)
#pragma unroll
      for (int nf = 0; nf < 2; ++nf) {
        acc[mf][nf] = MFMA(a[mf][0], b0[nf][0], acc[mf][nf]);
        acc[mf][nf] = MFMA(a[mf][1], b0[nf][1], acc[mf][nf]);
      }
    __builtin_amdgcn_s_setprio(0);
    BARRIER();
    bf16x8 b2[2][2];
#pragma unroll
    for (int nf = 0; nf < 2; ++nf) { b2[nf][0] = RB1(cur, 2 + nf, 0); b2[nf][1] = RB1(cur, 2 + nf, 1); }
    if (t + 2 < NT) STG_A1(stg, t + 2);
    BARRIER(); LGKM0();
    __builtin_amdgcn_s_setprio(1);
#pragma unroll
    for (int mf = 0; mf < 4; ++mf)
#pragma unroll
      for (int nf = 0; nf < 2; ++nf) {
        acc[mf][2 + nf] = MFMA(a[mf][0], b2[nf][0], acc[mf][2 + nf]);
        acc[mf][2 + nf] = MFMA(a[mf][1], b2[nf][1], acc[mf][2 + nf]);
      }
    __builtin_amdgcn_s_setprio(0);
    if (t + 2 < NT) { VMCNT(6); }
    else if (t + 2 == NT) { VMCNT(0); }
    BARRIER();
  }
#undef STG_A1
#undef STG_B1
#undef RA1
#undef RB1

#pragma unroll
  for (int mf = 0; mf < 4; ++mf)
#pragma unroll
    for (int rr = 0; rr < 4; ++rr) {
      const int m = row0 + (wm << 6) + (mf << 4) + (g << 2) + rr;
#pragma unroll
      for (int nf = 0; nf < 4; ++nf)
        C[(size_t)m * DMODEL + col0 + (wn << 6) + (nf << 4) + r15] = acc[mf][nf][rr];
    }
}

// ---------------- V transpose via LDS tile: (B*S, KVD) -> (B, NKV, HDIM, S) ----------------
__global__ __launch_bounds__(256) void transpose_v(const unsigned short* __restrict__ V,
                                                   unsigned short* __restrict__ Vt) {
  __shared__ unsigned short t[64][80];
  const int bid = blockIdx.x;       // 512 = 2*8*32
  const int st_ = bid & 31;
  const int kvh = (bid >> 5) & 7;
  const int b = bid >> 8;
  const int tid = threadIdx.x;
#pragma unroll
  for (int p = 0; p < 2; ++p) {
    int idx = p * 2048 + tid * 8;
    int r = idx >> 6, c = idx & 63;
    u16x8 v = *(const u16x8*)(V + (size_t)(b * SEQ + st_ * 64 + r) * KVD + kvh * 64 + c);
#pragma unroll
    for (int jj = 0; jj < 8; ++jj) t[c + jj][r] = v[jj];
  }
  __syncthreads();
#pragma unroll
  for (int p = 0; p < 2; ++p) {
    int idx = p * 2048 + tid * 8;
    int d = idx >> 6, s = idx & 63;
    u16x8 v = *(const u16x8*)&t[d][s];
    *(u16x8*)(Vt + (size_t)((b * NKV + kvh) * HDIM + d) * SEQ + st_ * 64 + s) = v;
  }
}

// ---------------- Flash attention (causal, GQA) ----------------
__global__ __launch_bounds__(256) void attn_fwd(const unsigned short* __restrict__ Q,
                                                const unsigned short* __restrict__ K,
                                                const unsigned short* __restrict__ Vt,
                                                unsigned short* __restrict__ O) {
  __shared__ __align__(16) unsigned short Kls[2][64 * 64];
  __shared__ __align__(16) unsigned short Vls[2][64 * 64];
  const int bid = blockIdx.x;
  const int xcd = bid & 7;
  const int within = bid >> 3;             // 0..127
  const int grp = xcd * 2 + (within >> 6); // 0..15 = (b,kvh)
  const int w64 = within & 63;
  const int j = w64 & 15;                  // pair: tiles j and 31-j
  const int hsub = w64 >> 4;
  const int b = grp >> 3, kvh = grp & 7;
  const int h = kvh * 4 + hsub;
  const int wave = threadIdx.x >> 6, lane = threadIdx.x & 63;
  const int g = lane >> 4, r15 = lane & 15;
  const int sr = lane >> 3;
  const int sc = (((lane & 7) << 4) ^ (sr << 4)) >> 1;  // pre-swizzled src col (shorts)
  const unsigned short* kbase = K + (size_t)b * SEQ * KVD + kvh * HDIM;
  const unsigned short* vbase = Vt + (size_t)((b * NKV + kvh) * HDIM) * SEQ;

  union { u16x8 s; bf16x8 v; } one8;
#pragma unroll
  for (int z = 0; z < 8; ++z) one8.s[z] = 0x3F80;  // bf16 1.0

  auto STAGE = [&](int bi, int kbv) {
#pragma unroll
    for (int i = 0; i < 2; ++i) {
      const int r = wave * 16 + i * 8;
      gload16(kbase + (size_t)(kbv + r + sr) * KVD + sc, &Kls[bi][r * 64]);
      gload16(vbase + (size_t)(r + sr) * SEQ + kbv + sc, &Vls[bi][r * 64]);
    }
  };

#pragma unroll 1
  for (int sel = 0; sel < 2; ++sel) {
    const int qt = sel ? (31 - j) : j;
    const int qrow0 = qt * 64 + wave * 16;
    const unsigned short* qp = Q + (size_t)(b * SEQ + qrow0 + r15) * DMODEL + h * HDIM;
    bf16x8 q0 = *(const bf16x8*)(qp + g * 8);
    bf16x8 q1 = *(const bf16x8*)(qp + 32 + g * 8);
    f32x4 oacc[4] = {};
    f32x4 lacc = {};
    const int kend = (qt + 1) * 64;
    __syncthreads();           // prior-tile reads drained before restaging
    STAGE(0, 0);
    int buf = 0;
    for (int kb = 0; kb < kend; kb += 64) {
      __syncthreads();         // staged loads for buf complete; buf^1 reads done
      if (kb + 64 < kend) STAGE(buf ^ 1, kb + 64);
      const char* Kc = (const char*)&Kls[buf][0];
      const char* Vc = (const char*)&Vls[buf][0];
      f32x4 s[4];
      __builtin_amdgcn_s_setprio(1);
#pragma unroll
      for (int f = 0; f < 4; ++f) {
        const int r = f * 16 + r15;
        const int sw = (r & 7) << 4;
        bf16x8 k0 = *(const bf16x8*)(Kc + r * 128 + ((g * 16) ^ sw));
        bf16x8 k1 = *(const bf16x8*)(Kc + r * 128 + ((64 + g * 16) ^ sw));
        f32x4 z = {};
        s[f] = MFMA(k1, q1, MFMA(k0, q0, z));
      }
      __builtin_amdgcn_s_setprio(0);
      if (kb + 64 == kend) {   // diagonal tile: causal mask
        const int q = qrow0 + r15;
#pragma unroll
        for (int f = 0; f < 4; ++f)
#pragma unroll
          for (int rr = 0; rr < 4; ++rr)
            if (kb + f * 16 + g * 4 + rr > q) s[f][rr] = -1e30f;
      }
#pragma unroll
      for (int f = 0; f < 4; ++f)
#pragma unroll
        for (int rr = 0; rr < 4; ++rr) s[f][rr] = exp2v(s[f][rr]);
      // C-layout -> A-layout in-register (cvt_pk + permlane swaps)
      bf16x8 p1, p2;
      {
        union { bf16x8 v; unsigned u[4]; } P1, P2;
        unsigned a0 = cvtpk(s[0][0], s[0][1]), b0 = cvtpk(s[1][0], s[1][1]);
        pl32(a0, b0); pl16(a0, b0);
        unsigned a1 = cvtpk(s[0][2], s[0][3]), b1 = cvtpk(s[1][2], s[1][3]);
        pl32(a1, b1); pl16(a1, b1);
        P1.u[0] = a0; P1.u[1] = a1; P1.u[2] = b0; P1.u[3] = b1;
        unsigned a2 = cvtpk(s[2][0], s[2][1]), b2 = cvtpk(s[3][0], s[3][1]);
        pl32(a2, b2); pl16(a2, b2);
        unsigned a3 = cvtpk(s[2][2], s[2][3]), b3 = cvtpk(s[3][2], s[3][3]);
        pl32(a3, b3); pl16(a3, b3);
        P2.u[0] = a2; P2.u[1] = a3; P2.u[2] = b2; P2.u[3] = b3;
        p1 = P1.v; p2 = P2.v;
      }
      // l[q] accumulated on MFMA pipe: D rows (g*4+rr) = q, cols identical
      lacc = MFMA(p2, one8.v, MFMA(p1, one8.v, lacc));
      __builtin_amdgcn_s_setprio(1);
#pragma unroll
      for (int dc = 0; dc < 4; ++dc) {
        const int r = dc * 16 + r15;
        const int sw = (r & 7) << 4;
        bf16x8 v0 = *(const bf16x8*)(Vc + r * 128 + ((g * 16) ^ sw));
        bf16x8 v1 = *(const bf16x8*)(Vc + r * 128 + ((64 + g * 16) ^ sw));
        oacc[dc] = MFMA(p2, v1, MFMA(p1, v0, oacc[dc]));
      }
      __builtin_amdgcn_s_setprio(0);
      buf ^= 1;
    }
    float rls[4];
#pragma unroll
    for (int rr = 0; rr < 4; ++rr) rls[rr] = 1.0f / lacc[rr];
    unsigned short* optr = O + (size_t)(b * SEQ + qrow0) * DMODEL + h * HDIM;
#pragma unroll
    for (int dc = 0; dc < 4; ++dc)
#pragma unroll
      for (int rr = 0; rr < 4; ++rr)
        optr[(size_t)(g * 4 + rr) * DMODEL + dc * 16 + r15] = f2bf(oacc[dc][rr] * rls[rr]);
  }
}

extern "C" void kernel_launch(void* const* d_in, const int* in_sizes, int n_in,
                              void* d_out, int out_size, void* d_ws, size_t ws_size,
                              hipStream_t stream) {
  const float* x  = (const float*)d_in[0];
  const float* Wq = (const float*)d_in[1];
  const float* Wk = (const float*)d_in[2];
  const float* Wv = (const float*)d_in[3];
  const float* Wo = (const float*)d_in[4];

  char* ws = (char*)d_ws;
  unsigned short* xb  = (unsigned short*)(ws);                    // 16 MiB
  unsigned short* Wqb = (unsigned short*)(ws + (16u << 20));      // 8 MiB
  unsigned short* Wkb = (unsigned short*)(ws + (24u << 20));      // 2 MiB
  unsigned short* Wvb = (unsigned short*)(ws + (26u << 20));      // 2 MiB
  unsigned short* Wob = (unsigned short*)(ws + (28u << 20));      // 8 MiB
  unsigned short* Qb  = (unsigned short*)(ws + (36u << 20));      // 16 MiB
  unsigned short* Kb  = (unsigned short*)(ws + (52u << 20));      // 4 MiB
  unsigned short* Vb  = (unsigned short*)(ws + (56u << 20));      // 4 MiB
  unsigned short* Vtb = (unsigned short*)(ws + (60u << 20));      // 4 MiB
  unsigned short* AO  = (unsigned short*)(ws + (64u << 20));      // 16 MiB
  float* ct = (float*)(ws + (80u << 20));                         // 256 KiB
  float* st = (float*)(ws + (81u << 20));                         // 256 KiB

  conv_all<<<18688, 256, 0, stream>>>(x, Wq, Wk, Wv, Wo, xb, Wqb, Wkb, Wvb, Wob, ct, st);

  gemm_qkv8p<<<768, 512, 0, stream>>>(xb, Wqb, Wkb, Wvb, Qb, Kb, Vb, ct, st);
  transpose_v<<<512, 256, 0, stream>>>(Vb, Vtb);

  attn_fwd<<<1024, 256, 0, stream>>>(Qb, Kb, Vtb, AO);

  gemm_out128<<<256, 512, 0, stream>>>(AO, Wob, (float*)d_out);
}

// Round 9
// 196.058 us; speedup vs baseline: 1.0847x; 1.0213x over previous
//
#include <hip/hip_runtime.h>
#include <math.h>

#define BATCHN 2
#define SEQ 2048
#define DMODEL 2048
#define NH 32
#define NKV 8
#define HDIM 64
#define KVD 512          // NKV*HDIM
#define ROWS 4096        // BATCHN*SEQ

typedef __bf16 bf16x8 __attribute__((ext_vector_type(8)));
typedef float f32x4 __attribute__((ext_vector_type(4)));
typedef unsigned short u16x8 __attribute__((ext_vector_type(8)));

#define MFMA(a, b, c) __builtin_amdgcn_mfma_f32_16x16x32_bf16(a, b, c, 0, 0, 0)

__device__ __forceinline__ unsigned short f2bf(float f) {
  union { float f; unsigned u; } v; v.f = f;
  unsigned u = v.u;
  u += 0x7fffu + ((u >> 16) & 1u);   // RNE
  return (unsigned short)(u >> 16);
}

__device__ __forceinline__ unsigned cvtpk(float a, float b) {
  unsigned r;
  asm("v_cvt_pk_bf16_f32 %0, %1, %2" : "=v"(r) : "v"(a), "v"(b));
  return r;
}
__device__ __forceinline__ void pl32(unsigned& a, unsigned& b) {
  asm("v_permlane32_swap_b32 %0, %1" : "+v"(a), "+v"(b));
}
__device__ __forceinline__ void pl16(unsigned& a, unsigned& b) {
  asm("v_permlane16_swap_b32 %0, %1" : "+v"(a), "+v"(b));
}
__device__ __forceinline__ float exp2v(float x) {
  float r;
  asm("v_exp_f32 %0, %1" : "=v"(r) : "v"(x));
  return r;
}

// async global->LDS; dest = wave-uniform base, lane*16B implicit (HW rule)
__device__ __forceinline__ void gload16(const void* g, void* l) {
  __builtin_amdgcn_global_load_lds((const __attribute__((address_space(1))) unsigned int*)g,
                                   (__attribute__((address_space(3))) unsigned int*)l, 16, 0, 0);
}

#define FENCE() asm volatile("" ::: "memory")
#define BARRIER() do { FENCE(); __builtin_amdgcn_s_barrier(); FENCE(); } while (0)
#define VMCNT(n) asm volatile("s_waitcnt vmcnt(" #n ")" ::: "memory")

// ---------------- fused fp32->bf16 conversions + RoPE tables (one launch) ----------------
__global__ __launch_bounds__(256) void conv_all(const float* __restrict__ x,
                                                const float* __restrict__ Wq,
                                                const float* __restrict__ Wk,
                                                const float* __restrict__ Wv,
                                                const float* __restrict__ Wo,
                                                unsigned short* __restrict__ xb,
                                                unsigned short* __restrict__ Wqb,
                                                unsigned short* __restrict__ Wkb,
                                                unsigned short* __restrict__ Wvb,
                                                unsigned short* __restrict__ Wob,
                                                float* __restrict__ ct,
                                                float* __restrict__ st) {
  int i = blockIdx.x * 256 + threadIdx.x;
  const float* in;
  unsigned short* out;
  int off;
  if (i < 2097152)      { in = x;  out = xb;  off = i; }
  else if (i < 3145728) { in = Wq; out = Wqb; off = i - 2097152; }
  else if (i < 3407872) { in = Wk; out = Wkb; off = i - 3145728; }
  else if (i < 3670016) { in = Wv; out = Wvb; off = i - 3407872; }
  else if (i < 4718592) { in = Wo; out = Wob; off = i - 3670016; }
  else {
    int t = i - 4718592;  // 0..65535 : RoPE tables [SEQ][32]
    int s = t >> 5, f = t & 31;
    float inv = __expf(-(float)f * (9.210340371976184f / 32.0f));  // 10000^(-f/32)
    float ang = (float)s * inv;
    ct[t] = cosf(ang);
    st[t] = sinf(ang);
    return;
  }
  float4 v = ((const float4*)in)[off];
  ushort4 o;
  o.x = f2bf(v.x); o.y = f2bf(v.y); o.z = f2bf(v.z); o.w = f2bf(v.w);
  ((ushort4*)out)[off] = o;
}

// ================= QKV GEMM v3: 256x256, BK=64, 8 waves, interleaved half-tile slots =================
// A-slot s = wave-local rows s*64..s*64+63 (both wm); B-slot s = nf-pair s (all wn).
// Phases: Q(0,0) reads A0,B0 (12 ds); Q(1,0) reads A1 (8); Q(1,1) reads B1 (4); Q(0,1) 0 reads.
// Stages: p1->A0(t+1), p2->B1(t+1), p3->B0(t+2), p4->A1(t+2); all land in freed slots.
// One vmcnt(4) per K-tile at p4 drains exactly tile t+1; prefetch depth 4-6 phases.
__global__ __launch_bounds__(512, 2) void gemm_qkv256b(const unsigned short* __restrict__ A,
                                                       const unsigned short* __restrict__ Bq,
                                                       const unsigned short* __restrict__ Bk,
                                                       const unsigned short* __restrict__ Bv,
                                                       unsigned short* __restrict__ Qo,
                                                       unsigned short* __restrict__ Ko,
                                                       unsigned short* __restrict__ Vo,
                                                       const float* __restrict__ ct,
                                                       const float* __restrict__ st) {
  __shared__ __align__(16) unsigned short Als[2 * 2 * 2 * 4096];  // [buf][slotA][wm][64][64]
  __shared__ __align__(16) unsigned short Bls[2 * 2 * 8192];      // [buf][slotB][128][64]
  const int tid = threadIdx.x, lane = tid & 63, wv = tid >> 6;
  const int wm = wv >> 2, wn = wv & 3;
  const int g = lane >> 4, r15 = lane & 15;
  // 192 blocks; XCD chunks of 24 = 2 bm x 12 bn, bn-fastest (A L2-resident)
  const int wgid = (blockIdx.x & 7) * 24 + (blockIdx.x >> 3);
  const int bm = wgid / 12, bn = wgid % 12;
  const int row0 = bm << 8;
  const unsigned short* Bp;
  unsigned short* Outb;
  int col0, ldo, rope, qsc;
  if (bn < 8)       { Bp = Bq; Outb = Qo; col0 = bn << 8;        ldo = DMODEL; rope = 1; qsc = 1; }
  else if (bn < 10) { Bp = Bk; Outb = Ko; col0 = (bn - 8) << 8;  ldo = KVD;    rope = 1; qsc = 0; }
  else              { Bp = Bv; Outb = Vo; col0 = (bn - 10) << 8; ldo = KVD;    rope = 0; qsc = 0; }
  // staging: thread -> row (tid>>3), pre-swizzled 16B granule (tid&7)^(row&7)
  const int srl = tid >> 3;
  const int swz = ((tid & 7) ^ (srl & 7)) << 3;
  const unsigned short* gA = A + (size_t)(row0 + srl) * DMODEL + swz;
  const unsigned short* gB = Bp + (size_t)(col0 + ((srl >> 5) << 6) + (srl & 31)) * DMODEL + swz;
  const int ldsw = (wv << 9);   // wave-uniform dest offset (shorts)

  f32x4 acc[8][4];
#pragma unroll
  for (int i = 0; i < 8; ++i)
#pragma unroll
    for (int jj = 0; jj < 4; ++jj) acc[i][jj] = (f32x4){0.f, 0.f, 0.f, 0.f};

#define STG_A(buf, s, kt) do { \
    gload16(gA + (size_t)((s) * 64) * DMODEL + (kt) * 64, &Als[((((buf)*2+(s))*2+0) << 12) + ldsw]); \
    gload16(gA + (size_t)(128 + (s) * 64) * DMODEL + (kt) * 64, &Als[((((buf)*2+(s))*2+1) << 12) + ldsw]); } while (0)
#define STG_B(buf, s, kt) do { \
    gload16(gB + (size_t)((s) * 32) * DMODEL + (kt) * 64, &Bls[(((buf)*2+(s)) << 13) + ldsw]); \
    gload16(gB + (size_t)(128 + (s) * 32) * DMODEL + (kt) * 64, &Bls[(((buf)*2+(s)) << 13) + 4096 + ldsw]); } while (0)
#define RA(buf, s, mfl, kk) (*(const bf16x8*)&Als[((((buf)*2+(s))*2+wm) << 12) + ((mfl)*16 + r15)*64 + \
                              (((((kk)<<2)+g) ^ (r15 & 7)) << 3)])
#define RB(buf, s, nfl, kk) (*(const bf16x8*)&Bls[(((buf)*2+(s)) << 13) + (wn*32 + (nfl)*16 + r15)*64 + \
                              (((((kk)<<2)+g) ^ (r15 & 7)) << 3)])

  // prologue: tile0 all slots; tile1 {B0, A1}; leave those 4 loads in flight
  STG_A(0, 0, 0); STG_B(0, 0, 0); STG_A(0, 1, 0); STG_B(0, 1, 0);
  STG_B(1, 0, 1); STG_A(1, 1, 1);
  VMCNT(4);
  BARRIER();

  const int NT = DMODEL / 64;  // 32
  for (int t = 0; t < NT; ++t) {
    const int cur = t & 1, nxt = cur ^ 1;
    bf16x8 a0[4][2], a1[4][2], b0[2][2], b1[2][2];
    // ---- p1: Q(0,0) — read A0,B0; stage A0(t+1) ----
#pragma unroll
    for (int mfl = 0; mfl < 4; ++mfl) { a0[mfl][0] = RA(cur, 0, mfl, 0); a0[mfl][1] = RA(cur, 0, mfl, 1); }
#pragma unroll
    for (int nfl = 0; nfl < 2; ++nfl) { b0[nfl][0] = RB(cur, 0, nfl, 0); b0[nfl][1] = RB(cur, 0, nfl, 1); }
    if (t + 1 < NT) STG_A(nxt, 0, t + 1);
    __builtin_amdgcn_s_setprio(1);
#pragma unroll
    for (int mfl = 0; mfl < 4; ++mfl)
#pragma unroll
      for (int nfl = 0; nfl < 2; ++nfl) {
        acc[mfl][nfl] = MFMA(a0[mfl][0], b0[nfl][0], acc[mfl][nfl]);
        acc[mfl][nfl] = MFMA(a0[mfl][1], b0[nfl][1], acc[mfl][nfl]);
      }
    __builtin_amdgcn_s_setprio(0);
    BARRIER();
    // ---- p2: Q(1,0) — read A1; stage B1(t+1) ----
#pragma unroll
    for (int mfl = 0; mfl < 4; ++mfl) { a1[mfl][0] = RA(cur, 1, mfl, 0); a1[mfl][1] = RA(cur, 1, mfl, 1); }
    if (t + 1 < NT) STG_B(nxt, 1, t + 1);
    __builtin_amdgcn_s_setprio(1);
#pragma unroll
    for (int mfl = 0; mfl < 4; ++mfl)
#pragma unroll
      for (int nfl = 0; nfl < 2; ++nfl) {
        acc[4 + mfl][nfl] = MFMA(a1[mfl][0], b0[nfl][0], acc[4 + mfl][nfl]);
        acc[4 + mfl][nfl] = MFMA(a1[mfl][1], b0[nfl][1], acc[4 + mfl][nfl]);
      }
    __builtin_amdgcn_s_setprio(0);
    BARRIER();
    // ---- p3: Q(1,1) — read B1; stage B0(t+2) ----
#pragma unroll
    for (int nfl = 0; nfl < 2; ++nfl) { b1[nfl][0] = RB(cur, 1, nfl, 0); b1[nfl][1] = RB(cur, 1, nfl, 1); }
    if (t + 2 < NT) STG_B(cur, 0, t + 2);
    __builtin_amdgcn_s_setprio(1);
#pragma unroll
    for (int mfl = 0; mfl < 4; ++mfl)
#pragma unroll
      for (int nfl = 0; nfl < 2; ++nfl) {
        acc[4 + mfl][2 + nfl] = MFMA(a1[mfl][0], b1[nfl][0], acc[4 + mfl][2 + nfl]);
        acc[4 + mfl][2 + nfl] = MFMA(a1[mfl][1], b1[nfl][1], acc[4 + mfl][2 + nfl]);
      }
    __builtin_amdgcn_s_setprio(0);
    BARRIER();
    // ---- p4: Q(0,1) — no reads (a0,b1 held); stage A1(t+2); counted drain ----
    if (t + 2 < NT) STG_A(cur, 1, t + 2);
    __builtin_amdgcn_s_setprio(1);
#pragma unroll
    for (int mfl = 0; mfl < 4; ++mfl)
#pragma unroll
      for (int nfl = 0; nfl < 2; ++nfl) {
        acc[mfl][2 + nfl] = MFMA(a0[mfl][0], b1[nfl][0], acc[mfl][2 + nfl]);
        acc[mfl][2 + nfl] = MFMA(a0[mfl][1], b1[nfl][1], acc[mfl][2 + nfl]);
      }
    __builtin_amdgcn_s_setprio(0);
    if (t + 2 < NT) { VMCNT(4); }
    else if (t + 1 < NT) { VMCNT(0); }
    BARRIER();
  }
#undef STG_A
#undef STG_B
#undef RA
#undef RB

  const float QS = 0.18033688011112042f;  // 0.125 * log2(e)
#pragma unroll
  for (int mf = 0; mf < 8; ++mf) {
#pragma unroll
    for (int rr = 0; rr < 4; ++rr) {
      const int m = row0 + (wm << 7) + (mf << 4) + (g << 2) + rr;
      const float* ctr = ct + ((m & (SEQ - 1)) << 5);
      const float* str = st + ((m & (SEQ - 1)) << 5);
#pragma unroll
      for (int nf = 0; nf < 4; ++nf) {
        const int n = col0 + (wn << 6) + (nf << 4) + r15;
        float v = acc[mf][nf][rr];
        float p = __shfl_xor(v, 1);
        if (rope) {
          int fi = (n & 63) >> 1;
          float c = ctr[fi], sn = str[fi];
          v = (lane & 1) ? (p * sn + v * c) : (v * c - p * sn);
        }
        if (qsc) v *= QS;
        Outb[(size_t)m * ldo + n] = f2bf(v);
      }
    }
  }
}

// ================= out-proj GEMM: 128x256 tile, BK=64, 8 waves, 2-phase, TRIPLE buffer =================
__global__ __launch_bounds__(512) void gemm_out128(const unsigned short* __restrict__ A,
                                                   const unsigned short* __restrict__ B,
                                                   float* __restrict__ C) {
  __shared__ __align__(16) unsigned short Als[3][8192];      // [buf][128*64]
  __shared__ __align__(16) unsigned short Bls[3][2][8192];   // [buf][half][128*64]
  const int tid = threadIdx.x, lane = tid & 63, wv = tid >> 6;
  const int wm = wv >> 2, wn = wv & 3;
  const int g = lane >> 4, r15 = lane & 15;
  const int wgid = (blockIdx.x & 7) * 32 + (blockIdx.x >> 3);
  const int bm = wgid >> 3, bn = wgid & 7;
  const int row0 = bm << 7, col0 = bn << 8;
  const int srl = tid >> 3;
  const int sgc = ((tid & 7) ^ (srl & 7)) << 3;
  const unsigned short* gA = A + (size_t)(row0 + srl) * DMODEL + sgc;
  const unsigned short* gB = B + (size_t)(col0 + srl) * DMODEL + sgc;

  f32x4 acc[4][4];
#pragma unroll
  for (int i = 0; i < 4; ++i)
#pragma unroll
    for (int jj = 0; jj < 4; ++jj) acc[i][jj] = (f32x4){0.f, 0.f, 0.f, 0.f};

#define STG_A1(buf, kt) do { \
    gload16(gA + (size_t)(kt) * 64, &Als[buf][(wv << 9)]); \
    gload16(gA + (size_t)64 * DMODEL + (size_t)(kt) * 64, &Als[buf][4096 + (wv << 9)]); } while (0)
#define STG_B1(buf, h, kt) do { \
    gload16(gB + (size_t)((h) * 128) * DMODEL + (kt) * 64, &Bls[buf][h][(wv << 9)]); \
    gload16(gB + (size_t)((h) * 128 + 64) * DMODEL + (kt) * 64, &Bls[buf][h][4096 + (wv << 9)]); } while (0)
#define RA1(buf, mf, kk) (*(const bf16x8*)&Als[buf][((wm << 6) + (mf) * 16 + r15) * 64 + \
                           (((((kk) << 2) + g) ^ (r15 & 7)) << 3)])
#define RB1(buf, nf, kk) (*(const bf16x8*)&Bls[buf][wn >> 1][((wn & 1) * 64 + (nf) * 16 + r15) * 64 + \
                           (((((kk) << 2) + g) ^ (r15 & 7)) << 3)])

  STG_B1(0, 0, 0); STG_B1(0, 1, 0); STG_A1(0, 0);
  STG_B1(1, 0, 1); STG_B1(1, 1, 1); STG_A1(1, 1);
  VMCNT(6);
  BARRIER();

  const int NT = DMODEL / 64;  // 32
  for (int t = 0; t < NT; ++t) {
    const int cur = t % 3;
    const int stg = (t + 2) % 3;
    bf16x8 a[4][2], b0[2][2];
#pragma unroll
    for (int mf = 0; mf < 4; ++mf) { a[mf][0] = RA1(cur, mf, 0); a[mf][1] = RA1(cur, mf, 1); }
#pragma unroll
    for (int nf = 0; nf < 2; ++nf) { b0[nf][0] = RB1(cur, nf, 0); b0[nf][1] = RB1(cur, nf, 1); }
    if (t + 2 < NT) { STG_B1(stg, 0, t + 2); STG_B1(stg, 1, t + 2); }
    BARRIER();
    __builtin_amdgcn_s_setprio(1);
#pragma unroll
    for (int mf = 0; mf < 4; ++mf)
#pragma unroll
      for (int nf = 0; nf < 2; ++nf) {
        acc[mf][nf] = MFMA(a[mf][0], b0[nf][0], acc[mf][nf]);
        acc[mf][nf] = MFMA(a[mf][1], b0[nf][1], acc[mf][nf]);
      }
    __builtin_amdgcn_s_setprio(0);
    BARRIER();
    bf16x8 b2[2][2];
#pragma unroll
    for (int nf = 0; nf < 2; ++nf) { b2[nf][0] = RB1(cur, 2 + nf, 0); b2[nf][1] = RB1(cur, 2 + nf, 1); }
    if (t + 2 < NT) STG_A1(stg, t + 2);
    BARRIER();
    __builtin_amdgcn_s_setprio(1);
#pragma unroll
    for (int mf = 0; mf < 4; ++mf)
#pragma unroll
      for (int nf = 0; nf < 2; ++nf) {
        acc[mf][2 + nf] = MFMA(a[mf][0], b2[nf][0], acc[mf][2 + nf]);
        acc[mf][2 + nf] = MFMA(a[mf][1], b2[nf][1], acc[mf][2 + nf]);
      }
    __builtin_amdgcn_s_setprio(0);
    if (t + 2 < NT) { VMCNT(6); }
    else if (t + 2 == NT) { VMCNT(0); }
    BARRIER();
  }
#undef STG_A1
#undef STG_B1
#undef RA1
#undef RB1

#pragma unroll
  for (int mf = 0; mf < 4; ++mf)
#pragma unroll
    for (int rr = 0; rr < 4; ++rr) {
      const int m = row0 + (wm << 6) + (mf << 4) + (g << 2) + rr;
#pragma unroll
      for (int nf = 0; nf < 4; ++nf)
        C[(size_t)m * DMODEL + col0 + (wn << 6) + (nf << 4) + r15] = acc[mf][nf][rr];
    }
}

// ---------------- V transpose via LDS tile: (B*S, KVD) -> (B, NKV, HDIM, S) ----------------
__global__ __launch_bounds__(256) void transpose_v(const unsigned short* __restrict__ V,
                                                   unsigned short* __restrict__ Vt) {
  __shared__ unsigned short t[64][80];
  const int bid = blockIdx.x;       // 512 = 2*8*32
  const int st_ = bid & 31;
  const int kvh = (bid >> 5) & 7;
  const int b = bid >> 8;
  const int tid = threadIdx.x;
#pragma unroll
  for (int p = 0; p < 2; ++p) {
    int idx = p * 2048 + tid * 8;
    int r = idx >> 6, c = idx & 63;
    u16x8 v = *(const u16x8*)(V + (size_t)(b * SEQ + st_ * 64 + r) * KVD + kvh * 64 + c);
#pragma unroll
    for (int jj = 0; jj < 8; ++jj) t[c + jj][r] = v[jj];
  }
  __syncthreads();
#pragma unroll
  for (int p = 0; p < 2; ++p) {
    int idx = p * 2048 + tid * 8;
    int d = idx >> 6, s = idx & 63;
    u16x8 v = *(const u16x8*)&t[d][s];
    *(u16x8*)(Vt + (size_t)((b * NKV + kvh) * HDIM + d) * SEQ + st_ * 64 + s) = v;
  }
}

// ---------------- Flash attention (causal, GQA) ----------------
__global__ __launch_bounds__(256) void attn_fwd(const unsigned short* __restrict__ Q,
                                                const unsigned short* __restrict__ K,
                                                const unsigned short* __restrict__ Vt,
                                                unsigned short* __restrict__ O) {
  __shared__ __align__(16) unsigned short Kls[2][64 * 64];
  __shared__ __align__(16) unsigned short Vls[2][64 * 64];
  const int bid = blockIdx.x;
  const int xcd = bid & 7;
  const int within = bid >> 3;             // 0..127
  const int grp = xcd * 2 + (within >> 6); // 0..15 = (b,kvh)
  const int w64 = within & 63;
  const int j = w64 & 15;                  // pair: tiles j and 31-j
  const int hsub = w64 >> 4;
  const int b = grp >> 3, kvh = grp & 7;
  const int h = kvh * 4 + hsub;
  const int wave = threadIdx.x >> 6, lane = threadIdx.x & 63;
  const int g = lane >> 4, r15 = lane & 15;
  const int sr = lane >> 3;
  const int sc = (((lane & 7) << 4) ^ (sr << 4)) >> 1;  // pre-swizzled src col (shorts)
  const unsigned short* kbase = K + (size_t)b * SEQ * KVD + kvh * HDIM;
  const unsigned short* vbase = Vt + (size_t)((b * NKV + kvh) * HDIM) * SEQ;

  union { u16x8 s; bf16x8 v; } one8;
#pragma unroll
  for (int z = 0; z < 8; ++z) one8.s[z] = 0x3F80;  // bf16 1.0

  auto STAGE = [&](int bi, int kbv) {
#pragma unroll
    for (int i = 0; i < 2; ++i) {
      const int r = wave * 16 + i * 8;
      gload16(kbase + (size_t)(kbv + r + sr) * KVD + sc, &Kls[bi][r * 64]);
      gload16(vbase + (size_t)(r + sr) * SEQ + kbv + sc, &Vls[bi][r * 64]);
    }
  };

#pragma unroll 1
  for (int sel = 0; sel < 2; ++sel) {
    const int qt = sel ? (31 - j) : j;
    const int qrow0 = qt * 64 + wave * 16;
    const unsigned short* qp = Q + (size_t)(b * SEQ + qrow0 + r15) * DMODEL + h * HDIM;
    bf16x8 q0 = *(const bf16x8*)(qp + g * 8);
    bf16x8 q1 = *(const bf16x8*)(qp + 32 + g * 8);
    f32x4 oacc[4] = {};
    f32x4 lacc = {};
    const int kend = (qt + 1) * 64;
    __syncthreads();           // prior-tile reads drained before restaging
    STAGE(0, 0);
    int buf = 0;
    for (int kb = 0; kb < kend; kb += 64) {
      __syncthreads();         // staged loads for buf complete; buf^1 reads done
      if (kb + 64 < kend) STAGE(buf ^ 1, kb + 64);
      const char* Kc = (const char*)&Kls[buf][0];
      const char* Vc = (const char*)&Vls[buf][0];
      f32x4 s[4];
      __builtin_amdgcn_s_setprio(1);
#pragma unroll
      for (int f = 0; f < 4; ++f) {
        const int r = f * 16 + r15;
        const int sw = (r & 7) << 4;
        bf16x8 k0 = *(const bf16x8*)(Kc + r * 128 + ((g * 16) ^ sw));
        bf16x8 k1 = *(const bf16x8*)(Kc + r * 128 + ((64 + g * 16) ^ sw));
        f32x4 z = {};
        s[f] = MFMA(k1, q1, MFMA(k0, q0, z));
      }
      __builtin_amdgcn_s_setprio(0);
      if (kb + 64 == kend) {   // diagonal tile: causal mask
        const int q = qrow0 + r15;
#pragma unroll
        for (int f = 0; f < 4; ++f)
#pragma unroll
          for (int rr = 0; rr < 4; ++rr)
            if (kb + f * 16 + g * 4 + rr > q) s[f][rr] = -1e30f;
      }
#pragma unroll
      for (int f = 0; f < 4; ++f)
#pragma unroll
        for (int rr = 0; rr < 4; ++rr) s[f][rr] = exp2v(s[f][rr]);
      // C-layout -> A-layout in-register (cvt_pk + permlane swaps)
      bf16x8 p1, p2;
      {
        union { bf16x8 v; unsigned u[4]; } P1, P2;
        unsigned a0 = cvtpk(s[0][0], s[0][1]), b0 = cvtpk(s[1][0], s[1][1]);
        pl32(a0, b0); pl16(a0, b0);
        unsigned a1 = cvtpk(s[0][2], s[0][3]), b1 = cvtpk(s[1][2], s[1][3]);
        pl32(a1, b1); pl16(a1, b1);
        P1.u[0] = a0; P1.u[1] = a1; P1.u[2] = b0; P1.u[3] = b1;
        unsigned a2 = cvtpk(s[2][0], s[2][1]), b2 = cvtpk(s[3][0], s[3][1]);
        pl32(a2, b2); pl16(a2, b2);
        unsigned a3 = cvtpk(s[2][2], s[2][3]), b3 = cvtpk(s[3][2], s[3][3]);
        pl32(a3, b3); pl16(a3, b3);
        P2.u[0] = a2; P2.u[1] = a3; P2.u[2] = b2; P2.u[3] = b3;
        p1 = P1.v; p2 = P2.v;
      }
      // l[q] accumulated on MFMA pipe: D rows (g*4+rr) = q, cols identical
      lacc = MFMA(p2, one8.v, MFMA(p1, one8.v, lacc));
      __builtin_amdgcn_s_setprio(1);
#pragma unroll
      for (int dc = 0; dc < 4; ++dc) {
        const int r = dc * 16 + r15;
        const int sw = (r & 7) << 4;
        bf16x8 v0 = *(const bf16x8*)(Vc + r * 128 + ((g * 16) ^ sw));
        bf16x8 v1 = *(const bf16x8*)(Vc + r * 128 + ((64 + g * 16) ^ sw));
        oacc[dc] = MFMA(p2, v1, MFMA(p1, v0, oacc[dc]));
      }
      __builtin_amdgcn_s_setprio(0);
      buf ^= 1;
    }
    float rls[4];
#pragma unroll
    for (int rr = 0; rr < 4; ++rr) rls[rr] = 1.0f / lacc[rr];
    unsigned short* optr = O + (size_t)(b * SEQ + qrow0) * DMODEL + h * HDIM;
#pragma unroll
    for (int dc = 0; dc < 4; ++dc)
#pragma unroll
      for (int rr = 0; rr < 4; ++rr)
        optr[(size_t)(g * 4 + rr) * DMODEL + dc * 16 + r15] = f2bf(oacc[dc][rr] * rls[rr]);
  }
}

extern "C" void kernel_launch(void* const* d_in, const int* in_sizes, int n_in,
                              void* d_out, int out_size, void* d_ws, size_t ws_size,
                              hipStream_t stream) {
  const float* x  = (const float*)d_in[0];
  const float* Wq = (const float*)d_in[1];
  const float* Wk = (const float*)d_in[2];
  const float* Wv = (const float*)d_in[3];
  const float* Wo = (const float*)d_in[4];

  char* ws = (char*)d_ws;
  unsigned short* xb  = (unsigned short*)(ws);                    // 16 MiB
  unsigned short* Wqb = (unsigned short*)(ws + (16u << 20));      // 8 MiB
  unsigned short* Wkb = (unsigned short*)(ws + (24u << 20));      // 2 MiB
  unsigned short* Wvb = (unsigned short*)(ws + (26u << 20));      // 2 MiB
  unsigned short* Wob = (unsigned short*)(ws + (28u << 20));      // 8 MiB
  unsigned short* Qb  = (unsigned short*)(ws + (36u << 20));      // 16 MiB
  unsigned short* Kb  = (unsigned short*)(ws + (52u << 20));      // 4 MiB
  unsigned short* Vb  = (unsigned short*)(ws + (56u << 20));      // 4 MiB
  unsigned short* Vtb = (unsigned short*)(ws + (60u << 20));      // 4 MiB
  unsigned short* AO  = (unsigned short*)(ws + (64u << 20));      // 16 MiB
  float* ct = (float*)(ws + (80u << 20));                         // 256 KiB
  float* st = (float*)(ws + (81u << 20));                         // 256 KiB

  conv_all<<<18688, 256, 0, stream>>>(x, Wq, Wk, Wv, Wo, xb, Wqb, Wkb, Wvb, Wob, ct, st);

  gemm_qkv256b<<<192, 512, 0, stream>>>(xb, Wqb, Wkb, Wvb, Qb, Kb, Vb, ct, st);
  transpose_v<<<512, 256, 0, stream>>>(Vb, Vtb);

  attn_fwd<<<1024, 256, 0, stream>>>(Qb, Kb, Vtb, AO);

  gemm_out128<<<256, 512, 0, stream>>>(AO, Wob, (float*)d_out);
}